// Round 11
// baseline (5712.906 us; speedup 1.0000x reference)
//
#include <hip/hip_runtime.h>

typedef __bf16 bf16x8 __attribute__((ext_vector_type(8)));
typedef __bf16 bf16x4 __attribute__((ext_vector_type(4)));
typedef __bf16 bf16x2 __attribute__((ext_vector_type(2)));
typedef float  f32x4  __attribute__((ext_vector_type(4)));
typedef unsigned short u16;

// ---------------- constants ----------------
#define BATCH   8192
#define NTOK    4
#define ROWS    (BATCH*NTOK)      // 32768
#define DIM     512
#define HEADS   8
#define DH      64
#define FFI     2048              // FF_INNER
#define DEPTH   12
#define LN_EPS  1e-5f

// ---------------- workspace layout (bytes) ----------------
static const size_t OFF_WQKV = 0;                               // (12, 640, 512) bf16
static const size_t SZ_WQKV  = 12ull*640*512*2;
static const size_t OFF_WTO  = OFF_WQKV + SZ_WQKV;
static const size_t SZ_WTO   = 12ull*512*512*2;
static const size_t OFF_WTF1 = OFF_WTO + SZ_WTO;                // interleaved layout (12,4096,512)
static const size_t SZ_WTF1  = 12ull*4096*512*2;
static const size_t OFF_WTF2 = OFF_WTF1 + SZ_WTF1;
static const size_t SZ_WTF2  = 12ull*512*2048*2;
static const size_t OFF_WTP  = OFF_WTF2 + SZ_WTF2;
static const size_t SZ_WTP   = 512ull*512*2;
static const size_t OFF_X    = OFF_WTP + SZ_WTP;                // f32 (32768,512)
static const size_t OFF_H    = OFF_X    + (size_t)ROWS*DIM*4;
static const size_t OFF_QKV  = OFF_H    + (size_t)ROWS*DIM*2;   // (32768,640) bf16; also y; act[0:67MB)
static const size_t OFF_AO   = OFF_QKV  + (size_t)ROWS*640*2;   // attn_out / act cont'd / hlast
static const size_t OFF_FLAG = OFF_AO   + (size_t)ROWS*DIM*2;
static const size_t WS_NEED  = OFF_FLAG + 256;                  // ~266 MB
// FF act buffer (16384 x 2048 bf16 = 67,108,864 B) aliases [OFF_QKV, OFF_QKV+67MB):
// spans qkv(41.9M)+ao(33.5M) = 75.5MB of dead-after-attn space. OK.

// ---------------- helpers ----------------
__device__ __forceinline__ float ldf(const void* p, size_t i, bool b16) {
  return b16 ? (float)((const __bf16*)p)[i] : ((const float*)p)[i];
}

__device__ __forceinline__ void gld_lds16(const void* g, void* l) {
  __builtin_amdgcn_global_load_lds((const __attribute__((address_space(1))) void*)g,
                                   (__attribute__((address_space(3))) void*)l, 16, 0, 0);
}

// 16-lane-group sum (xor butterfly, offsets 8..1 stay within the group)
__device__ __forceinline__ float gsum16(float v) {
  #pragma unroll
  for (int o = 8; o > 0; o >>= 1) v += __shfl_xor(v, o, 64);
  return v;
}

// full-wave reduce of a pair
__device__ __forceinline__ void wred2(float& a, float& b) {
  #pragma unroll
  for (int o = 32; o > 0; o >>= 1) { a += __shfl_xor(a, o, 64); b += __shfl_xor(b, o, 64); }
}

// ---------------- dtype detection: 1 block, writes flag (1 = bf16, 0 = fp32) ----------------
__global__ void detect_dtype(const unsigned int* __restrict__ w, int* __restrict__ flag) {
  __shared__ int cnt[4];
  int t = threadIdx.x;
  int c = 0;
  for (int i = t; i < 2048; i += 256) {
    unsigned int v = w[i];
    unsigned int lo = v & 0xFFFFu, hi = v >> 16;
    int elo = (int)((lo >> 7) & 0xFF), ehi = (int)((hi >> 7) & 0xFF);
    bool okl = (lo == 0u) || (elo >= 100 && elo <= 140);
    bool okh = (hi == 0u) || (ehi >= 100 && ehi <= 140);
    if (okl && okh) c++;
  }
  #pragma unroll
  for (int o = 32; o > 0; o >>= 1) c += __shfl_down(c, o, 64);
  if ((t & 63) == 0) cnt[t >> 6] = c;
  __syncthreads();
  if (t == 0) flag[0] = (cnt[0] + cnt[1] + cnt[2] + cnt[3] > 1024) ? 1 : 0;
}

// ---------------- weight transpose (K,N)->(N,K), optional ff1 interleave ----------------
__global__ void transpose_any(const void* __restrict__ in, u16* __restrict__ out,
                              int K, int N, size_t out_zsz, int rowoff, int mode,
                              const int* __restrict__ flag) {
  bool b16 = flag[0] != 0;
  __shared__ u16 tile[32][33];
  size_t iboff = (size_t)blockIdx.z * K * N;
  size_t oboff = (size_t)blockIdx.z * out_zsz;
  int n0 = blockIdx.x * 32, k0 = blockIdx.y * 32;
  int tx = threadIdx.x, ty = threadIdx.y;
  #pragma unroll
  for (int r = 0; r < 4; r++) {
    float v = ldf(in, iboff + (size_t)(k0 + ty*4 + r) * N + n0 + tx, b16);
    __bf16 bv = (__bf16)v;
    tile[ty*4+r][tx] = __builtin_bit_cast(u16, bv);
  }
  __syncthreads();
  int rbase;
  if (mode == 0) rbase = rowoff + n0;
  else {
    int s = (n0 >= 2048) ? 1 : 0;
    int np = n0 - s*2048;
    rbase = (np >> 7)*256 + ((np >> 5) & 3)*64 + s*32;   // n0 % 32 == 0
  }
  #pragma unroll
  for (int r = 0; r < 4; r++)
    out[oboff + (size_t)(rbase + ty*4 + r) * K + k0 + tx] = tile[tx][ty*4+r];
}

// ---------------- token assembly: x (B,4,512) f32 ----------------
__global__ void build_tokens(const void* __restrict__ text, const void* __restrict__ img,
                             const int* __restrict__ ts, const void* __restrict__ table,
                             const void* __restrict__ lq, float* __restrict__ x,
                             const int* __restrict__ flag) {
  bool b16 = flag[0] != 0;
  int b = blockIdx.x, t = threadIdx.x;
  float* xr = x + (size_t)b * NTOK * DIM;
  int tsb = ts[b];
  for (int e = t; e < DIM; e += 256) {
    xr[e]         = ldf(text,  (size_t)b * DIM + e, b16);
    xr[DIM + e]   = ldf(table, (size_t)tsb * DIM + e, b16);
    xr[2*DIM + e] = ldf(img,   (size_t)b * DIM + e, b16);
    xr[3*DIM + e] = ldf(lq,    (size_t)e, b16);
  }
}

// ---------------- LN: f32 row -> bf16 row (wave-per-row) ----------------
__global__ void ln_f32_bf16(const float* __restrict__ x, const void* __restrict__ g, size_t goff,
                            __bf16* __restrict__ out, const int* __restrict__ flag) {
  bool b16 = flag[0] != 0;
  int lane = threadIdx.x & 63;
  int row = blockIdx.x * 4 + (threadIdx.x >> 6);
  const float4* xr = (const float4*)(x + (size_t)row * DIM);
  float4 A4 = xr[lane*2], B4 = xr[lane*2 + 1];
  float v[8] = {A4.x, A4.y, A4.z, A4.w, B4.x, B4.y, B4.z, B4.w};
  float s = 0.f, s2 = 0.f;
  #pragma unroll
  for (int e = 0; e < 8; e++) { s += v[e]; s2 += v[e]*v[e]; }
  wred2(s, s2);
  float mean = s * (1.f/DIM);
  float var  = s2 * (1.f/DIM) - mean*mean;
  float rs = rsqrtf(var + LN_EPS);
  bf16x8 ov;
  #pragma unroll
  for (int e = 0; e < 8; e++)
    ov[e] = (__bf16)((v[e]-mean) * rs * ldf(g, goff + lane*8 + e, b16));
  *(bf16x8*)(out + (size_t)row * DIM + lane*8) = ov;
}

// ---------------- fused: x += LN(y; g1); h = LN(x; g2) (wave-per-row) ----------------
__global__ void ln_add_ln(const __bf16* __restrict__ y,
                          const void* __restrict__ g1, size_t g1off,
                          const void* __restrict__ g2, size_t g2off,
                          float* __restrict__ x, __bf16* __restrict__ h,
                          const int* __restrict__ flag) {
  bool b16 = flag[0] != 0;
  int lane = threadIdx.x & 63;
  int row = blockIdx.x * 4 + (threadIdx.x >> 6);
  bf16x8 y8 = *(const bf16x8*)(y + (size_t)row * DIM + lane*8);
  float yv[8];
  float s = 0.f, s2 = 0.f;
  #pragma unroll
  for (int e = 0; e < 8; e++) { yv[e] = (float)y8[e]; s += yv[e]; s2 += yv[e]*yv[e]; }
  wred2(s, s2);
  float mean = s * (1.f/DIM);
  float var  = s2 * (1.f/DIM) - mean*mean;
  float rs = rsqrtf(var + LN_EPS);
  float4* xr = (float4*)(x + (size_t)row * DIM);
  float4 XA = xr[lane*2], XB = xr[lane*2 + 1];
  float xv[8] = {XA.x, XA.y, XA.z, XA.w, XB.x, XB.y, XB.z, XB.w};
  #pragma unroll
  for (int e = 0; e < 8; e++)
    xv[e] += (yv[e]-mean) * rs * ldf(g1, g1off + lane*8 + e, b16);
  xr[lane*2]     = make_float4(xv[0], xv[1], xv[2], xv[3]);
  xr[lane*2 + 1] = make_float4(xv[4], xv[5], xv[6], xv[7]);
  float t = 0.f, t2 = 0.f;
  #pragma unroll
  for (int e = 0; e < 8; e++) { t += xv[e]; t2 += xv[e]*xv[e]; }
  wred2(t, t2);
  float mean2 = t * (1.f/DIM);
  float var2  = t2 * (1.f/DIM) - mean2*mean2;
  float rs2 = rsqrtf(var2 + LN_EPS);
  bf16x8 hv;
  #pragma unroll
  for (int e = 0; e < 8; e++)
    hv[e] = (__bf16)((xv[e]-mean2) * rs2 * ldf(g2, g2off + lane*8 + e, b16));
  *(bf16x8*)(h + (size_t)row * DIM + lane*8) = hv;
}

// ---------------- final LN on token-3 rows -> hlast (8192,512) bf16 (wave-per-b) ----------------
__global__ void ln_final(const float* __restrict__ x, const void* __restrict__ g,
                         __bf16* __restrict__ out, const int* __restrict__ flag) {
  bool b16 = flag[0] != 0;
  int lane = threadIdx.x & 63;
  int b = blockIdx.x * 4 + (threadIdx.x >> 6);
  int row = b*NTOK + 3;
  const float4* xr = (const float4*)(x + (size_t)row * DIM);
  float4 A4 = xr[lane*2], B4 = xr[lane*2 + 1];
  float v[8] = {A4.x, A4.y, A4.z, A4.w, B4.x, B4.y, B4.z, B4.w};
  float s = 0.f, s2 = 0.f;
  #pragma unroll
  for (int e = 0; e < 8; e++) { s += v[e]; s2 += v[e]*v[e]; }
  wred2(s, s2);
  float mean = s * (1.f/DIM);
  float var  = s2 * (1.f/DIM) - mean*mean;
  float rs = rsqrtf(var + LN_EPS);
  bf16x8 ov;
  #pragma unroll
  for (int e = 0; e < 8; e++)
    ov[e] = (__bf16)((v[e]-mean) * rs * ldf(g, (size_t)lane*8 + e, b16));
  *(bf16x8*)(out + (size_t)b * DIM + lane*8) = ov;
}

// ================= gemm8: EXACT r6 best config (256-tile, 1 block/CU, hfl schedule) ======
// Used for swiglu only (EPI 1). Do not perturb: r7-r10 A/Bs all regressed or null.
template<int BROWS, int EPI>
__global__ __launch_bounds__(512, 2) void gemm8(
    const __bf16* __restrict__ A, int lda,
    const __bf16* __restrict__ B, int ldb,
    void* __restrict__ Cv, int ldc, int K, const int* __restrict__ flag)
{
  constexpr int UNITS = (BROWS == 256) ? 4 : 3;
  constexpr int WCN   = (BROWS == 256) ? 4 : 2;
  constexpr int M_FR  = (BROWS == 256) ? 8 : 4;
  constexpr int QM    = M_FR / 4;
  __shared__ char ldsmem[2][(256 + BROWS) * 128];

  const int tid = threadIdx.x;
  const int wid = tid >> 6, lane = tid & 63;
  const int wr = wid / WCN, wc = wid % WCN;
  const int lr = lane & 15, lc = lane >> 4;
  const int sr = tid >> 3;
  const int cs = ((tid & 7) ^ (sr & 7)) * 8;
  const int bx = blockIdx.x, by = blockIdx.y;

  const __bf16* Ab = A + (size_t)by * 256 * lda;
  const __bf16* Bb = B + (size_t)bx * BROWS * ldb;

  f32x4 acc[M_FR][4] = {};
  const int NT = K >> 6;

  char* lds0 = ldsmem[0];
  char* lds1 = ldsmem[1];

  auto stage_unit = [&](int p, int kt, int u) {
    char* base = (p ? lds1 : lds0);
    if (u < 2) {
      const __bf16* s = Ab + (size_t)(u*128 + sr) * lda + kt*64 + cs;
      char* d = base + u*16384 + (wid << 10);
      gld_lds16(s, d);
      gld_lds16(s + (size_t)64 * lda, d + 8192);
    } else {
      const __bf16* s = Bb + (size_t)((u-2)*128 + sr) * ldb + kt*64 + cs;
      char* d = base + 32768 + (u-2)*16384 + (wid << 10);
      gld_lds16(s, d);
      gld_lds16(s + (size_t)64 * ldb, d + 8192);
    }
  };

  #pragma unroll
  for (int u = 0; u < UNITS; u++) stage_unit(0, 0, u);

  const int NIT = NT >> 1;
  for (int i = 0; i < NIT; i++) {
    const int t1 = 2*i + 1;
    const int t2 = (2*i + 2 < NT) ? (2*i + 2) : 0;
    #pragma unroll
    for (int hfl = 0; hfl < 2; hfl++) {
      char* cbase = hfl ? lds1 : lds0;
      const int sp = hfl ^ 1;
      const int st = hfl ? t2 : t1;
      bf16x8 bfr[4][2];
      #pragma unroll
      for (int q = 0; q < 4; q++) {
        if (q < UNITS) stage_unit(sp, st, q);
        if (q == 0) {
          asm volatile("s_waitcnt vmcnt(2)" ::: "memory");
          asm volatile("s_barrier" ::: "memory");
          #pragma unroll
          for (int f = 0; f < 4; f++)
            #pragma unroll
            for (int kk = 0; kk < 2; kk++) {
              int row = wc*64 + f*16 + lr;
              int ch = (kk*4 + lc) ^ (lr & 7);
              bfr[f][kk] = *(const bf16x8*)(cbase + 32768 + row*128 + ch*16);
            }
        }
        bf16x8 afr[QM][2];
        #pragma unroll
        for (int m2 = 0; m2 < QM; m2++)
          #pragma unroll
          for (int kk = 0; kk < 2; kk++) {
            int row = wr*(M_FR*16) + (q*QM + m2)*16 + lr;
            int ch = (kk*4 + lc) ^ (lr & 7);
            afr[m2][kk] = *(const bf16x8*)(cbase + row*128 + ch*16);
          }
        __builtin_amdgcn_s_setprio(1);
        #pragma unroll
        for (int m2 = 0; m2 < QM; m2++)
          #pragma unroll
          for (int n = 0; n < 4; n++)
            #pragma unroll
            for (int kk = 0; kk < 2; kk++)
              acc[q*QM + m2][n] = __builtin_amdgcn_mfma_f32_16x16x32_bf16(
                  afr[m2][kk], bfr[n][kk], acc[q*QM + m2][n], 0, 0, 0);
        __builtin_amdgcn_s_setprio(0);
        asm volatile("s_barrier" ::: "memory");
      }
    }
  }
  asm volatile("s_waitcnt vmcnt(0)" ::: "memory");  // drain dummy staging

  if (EPI == 1) {
    __bf16* Ob = (__bf16*)Cv;
    const int colb = bx*128 + wc*32 + lr;
    const int rowb = by*256 + wr*128 + lc*4;
    #pragma unroll
    for (int m = 0; m < M_FR; m++)
      #pragma unroll
      for (int rr = 0; rr < 4; rr++) {
        size_t ro = (size_t)(rowb + m*16 + rr) * ldc;
        #pragma unroll
        for (int fa = 0; fa < 2; fa++) {
          float a = acc[m][fa][rr], g = acc[m][fa+2][rr];
          Ob[ro + colb + fa*16] = (__bf16)(a * g / (1.f + __expf(-g)));
        }
      }
  } else {
    __bf16* Cb = (__bf16*)Cv;
    const int colb = bx*BROWS + wc*64 + lr;
    const int rowb = by*256 + wr*(M_FR*16) + lc*4;
    #pragma unroll
    for (int m = 0; m < M_FR; m++)
      #pragma unroll
      for (int rr = 0; rr < 4; rr++) {
        size_t ro = (size_t)(rowb + m*16 + rr) * ldc;
        #pragma unroll
        for (int n = 0; n < 4; n++) Cb[ro + colb + n*16] = (__bf16)acc[m][n][rr];
      }
  }
}

// ================= gemm4: fine 4-phase schedule at 2 blocks/CU (the un-run quadrant) =====
// 128x128 tile, 4 waves / 256 threads, LDS 2x32KB = 64KB -> 2 blocks/CU. Same per-phase
// {stage-unit || ds_read || MFMA || barrier} interleave and vmcnt(2) accounting as gemm8;
// the second independent block per CU provides off-phase waves to cover barrier stalls.
// EPI 0: bf16 store; EPI 2: f32 +=; EPI 3: bf16 or f32 per flag.
template<int EPI>
__global__ __launch_bounds__(256, 2) void gemm4(
    const __bf16* __restrict__ A, int lda,
    const __bf16* __restrict__ B, int ldb,
    void* __restrict__ Cv, int ldc, int K, const int* __restrict__ flag)
{
  __shared__ char ldsmem[2][32768];   // per buf: A 16KB @0, B 16KB @16384
  const int tid = threadIdx.x;
  const int wid = tid >> 6, lane = tid & 63;
  const int wr = wid >> 1, wc = wid & 1;
  const int lr = lane & 15, lc = lane >> 4;
  const int bx = blockIdx.x, by = blockIdx.y;
  const __bf16* Ab = A + (size_t)by * 128 * lda;
  const __bf16* Bb = B + (size_t)bx * 128 * ldb;
  f32x4 acc[4][4] = {};
  const int NT = K >> 6;
  const int srow = lane >> 3;                // 0..7
  const int scs  = ((lane & 7) ^ srow) * 8;  // pre-swizzled source chunk (elems)

  // unit u: 64 rows of A (u<2: rows u*64..) or B (u>=2: rows (u-2)*64..), 2 glds of 32 rows
  auto stage_unit = [&](int p, int kt, int u) {
    const bool isA = (u < 2);
    const int half = u & 1;
    const int r0 = half*64 + wid*8 + srow;
    const __bf16* S = isA ? (Ab + (size_t)r0 * lda + kt*64 + scs)
                          : (Bb + (size_t)r0 * ldb + kt*64 + scs);
    char* d = ldsmem[p] + (isA ? 0 : 16384) + half*8192 + (wid << 10);
    gld_lds16(S, d);
    gld_lds16(S + (size_t)32 * (isA ? lda : ldb), d + 4096);
  };

  #pragma unroll
  for (int u = 0; u < 4; u++) stage_unit(0, 0, u);

  for (int t = 0; t < NT; t++) {
    const int cp = t & 1, sp = cp ^ 1;
    char* cbase = ldsmem[cp];
    const int st = (t + 1 < NT) ? (t + 1) : 0;   // dummy re-stage keeps counts uniform
    bf16x8 bfr[4][2];
    #pragma unroll
    for (int q = 0; q < 4; q++) {
      stage_unit(sp, st, q);
      if (q == 0) {
        asm volatile("s_waitcnt vmcnt(2)" ::: "memory");
        asm volatile("s_barrier" ::: "memory");
        #pragma unroll
        for (int f = 0; f < 4; f++)
          #pragma unroll
          for (int kk = 0; kk < 2; kk++) {
            int row = wc*64 + f*16 + lr;
            int ch = (kk*4 + lc) ^ (lr & 7);
            bfr[f][kk] = *(const bf16x8*)(cbase + 16384 + row*128 + ch*16);
          }
      }
      bf16x8 afr[2];
      #pragma unroll
      for (int kk = 0; kk < 2; kk++) {
        int row = wr*64 + q*16 + lr;
        int ch = (kk*4 + lc) ^ (lr & 7);
        afr[kk] = *(const bf16x8*)(cbase + row*128 + ch*16);
      }
      __builtin_amdgcn_s_setprio(1);
      #pragma unroll
      for (int n = 0; n < 4; n++)
        #pragma unroll
        for (int kk = 0; kk < 2; kk++)
          acc[q][n] = __builtin_amdgcn_mfma_f32_16x16x32_bf16(
              afr[kk], bfr[n][kk], acc[q][n], 0, 0, 0);
      __builtin_amdgcn_s_setprio(0);
      asm volatile("s_barrier" ::: "memory");
    }
  }
  asm volatile("s_waitcnt vmcnt(0)" ::: "memory");  // drain dummy staging

  const int colb = bx*128 + wc*64 + lr;
  const int rowb = by*128 + wr*64 + lc*4;
  if (EPI == 2) {
    float* Xf = (float*)Cv;
    #pragma unroll
    for (int m = 0; m < 4; m++)
      #pragma unroll
      for (int rr = 0; rr < 4; rr++) {
        size_t ro = (size_t)(rowb + m*16 + rr) * ldc;
        #pragma unroll
        for (int n = 0; n < 4; n++) Xf[ro + colb + n*16] += acc[m][n][rr];
      }
  } else if (EPI == 0) {
    __bf16* Cb = (__bf16*)Cv;
    #pragma unroll
    for (int m = 0; m < 4; m++)
      #pragma unroll
      for (int rr = 0; rr < 4; rr++) {
        size_t ro = (size_t)(rowb + m*16 + rr) * ldc;
        #pragma unroll
        for (int n = 0; n < 4; n++) Cb[ro + colb + n*16] = (__bf16)acc[m][n][rr];
      }
  } else {
    bool b16o = flag[0] != 0;
    __bf16* Cb = (__bf16*)Cv;
    float*  Cf = (float*)Cv;
    #pragma unroll
    for (int m = 0; m < 4; m++)
      #pragma unroll
      for (int rr = 0; rr < 4; rr++) {
        size_t ro = (size_t)(rowb + m*16 + rr) * ldc;
        #pragma unroll
        for (int n = 0; n < 4; n++) {
          float val = acc[m][n][rr];
          if (b16o) Cb[ro + colb + n*16] = (__bf16)val; else Cf[ro + colb + n*16] = val;
        }
      }
  }
}

// ---------------- fused attention, 16-lane-group layout ----------------
__global__ __launch_bounds__(256) void attn_kernel(
    const __bf16* __restrict__ qkv,
    const void* __restrict__ nkv_all, int layer, const void* __restrict__ rel_emb,
    __bf16* __restrict__ ao, const int* __restrict__ flag)
{
  bool b16 = flag[0] != 0;
  const int tid = threadIdx.x;
  const int w = tid >> 6, l = tid & 63;
  const int g = l >> 4, c = l & 15;
  const int bh = blockIdx.x * 16 + w * 4 + g;
  const int b = bh >> 3, h = bh & 7;
  const bool rot = (c < 8);   // d = 4c..4c+3 < 32

  const float LN1E4_32 = 9.210340371976184f * (1.f/32.f);
  float inv0 = __expf(-(float)(4*c)     * LN1E4_32);
  float inv1 = __expf(-(float)(4*c + 2) * LN1E4_32);
  float cs0[4], sn0[4], cs1[4], sn1[4];
  #pragma unroll
  for (int t = 0; t < 4; t++) {
    __sincosf((float)t * inv0, &sn0[t], &cs0[t]);
    __sincosf((float)t * inv1, &sn1[t], &cs1[t]);
  }
  float rb[4];
  #pragma unroll
  for (int t = 0; t < 4; t++) rb[t] = ldf(rel_emb, (size_t)t * 8 + h, b16);

  float q[4][4];
  #pragma unroll
  for (int i = 0; i < 4; i++) {
    bf16x4 qv = *(const bf16x4*)(qkv + ((size_t)(b*NTOK + i)) * 640 + h*DH + c*4);
    float v0 = (float)qv[0], v1 = (float)qv[1], v2 = (float)qv[2], v3 = (float)qv[3];
    if (rot) {
      float n0 = v0*cs0[i] - v1*sn0[i], n1 = v1*cs0[i] + v0*sn0[i];
      float n2 = v2*cs1[i] - v3*sn1[i], n3 = v3*cs1[i] + v2*sn1[i];
      v0 = n0; v1 = n1; v2 = n2; v3 = n3;
    }
    q[i][0] = v0; q[i][1] = v1; q[i][2] = v2; q[i][3] = v3;
  }
  #pragma unroll
  for (int i = 0; i < 4; i++) {
    float ss = q[i][0]*q[i][0] + q[i][1]*q[i][1] + q[i][2]*q[i][2] + q[i][3]*q[i][3];
    float r = 1.f / fmaxf(sqrtf(gsum16(ss)), 1e-12f);
    #pragma unroll
    for (int e = 0; e < 4; e++) q[i][e] *= r;
  }

  float kk[5][4], vv[5][4];
  #pragma unroll
  for (int e = 0; e < 4; e++) {
    kk[0][e] = ldf(nkv_all, (size_t)layer*128 + c*4 + e, b16);
    vv[0][e] = ldf(nkv_all, (size_t)layer*128 + 64 + c*4 + e, b16);
  }
  #pragma unroll
  for (int j = 1; j < 5; j++) {
    const __bf16* base = qkv + ((size_t)(b*NTOK + j - 1)) * 640 + 512;
    bf16x4 kv4 = *(const bf16x4*)(base + c*4);
    bf16x4 vv4 = *(const bf16x4*)(base + 64 + c*4);
    float v0 = (float)kv4[0], v1 = (float)kv4[1], v2 = (float)kv4[2], v3 = (float)kv4[3];
    if (rot) {
      int t = j - 1;
      float n0 = v0*cs0[t] - v1*sn0[t], n1 = v1*cs0[t] + v0*sn0[t];
      float n2 = v2*cs1[t] - v3*sn1[t], n3 = v3*cs1[t] + v2*sn1[t];
      v0 = n0; v1 = n1; v2 = n2; v3 = n3;
    }
    kk[j][0] = v0; kk[j][1] = v1; kk[j][2] = v2; kk[j][3] = v3;
    #pragma unroll
    for (int e = 0; e < 4; e++) vv[j][e] = (float)vv4[e];
  }
  #pragma unroll
  for (int j = 0; j < 5; j++) {
    float ss = kk[j][0]*kk[j][0] + kk[j][1]*kk[j][1] + kk[j][2]*kk[j][2] + kk[j][3]*kk[j][3];
    float r = 1.f / fmaxf(sqrtf(gsum16(ss)), 1e-12f);
    #pragma unroll
    for (int e = 0; e < 4; e++) kk[j][e] *= r;
  }

  #pragma unroll
  for (int i = 0; i < 4; i++) {
    float sim[5];
    #pragma unroll
    for (int j = 0; j < 5; j++) {
      if (j > i + 1) break;
      float pp = q[i][0]*kk[j][0] + q[i][1]*kk[j][1] + q[i][2]*kk[j][2] + q[i][3]*kk[j][3];
      sim[j] = 16.f * gsum16(pp) + rb[(i - j > 0) ? (i - j) : 0];
    }
    float m = sim[0];
    #pragma unroll
    for (int j = 1; j < 5; j++) { if (j > i + 1) break; m = fmaxf(m, sim[j]); }
    float Z = 0.f, o0 = 0.f, o1 = 0.f, o2 = 0.f, o3 = 0.f;
    #pragma unroll
    for (int j = 0; j < 5; j++) {
      if (j > i + 1) break;
      float e = __expf(sim[j] - m);
      Z += e;
      o0 += e * vv[j][0]; o1 += e * vv[j][1]; o2 += e * vv[j][2]; o3 += e * vv[j][3];
    }
    float rz = 1.f / Z;
    bf16x4 ov = { (__bf16)(o0*rz), (__bf16)(o1*rz), (__bf16)(o2*rz), (__bf16)(o3*rz) };
    *(bf16x4*)(ao + ((size_t)(b*NTOK + i)) * DIM + h*DH + c*4) = ov;
  }
}

// ---------------- launch ----------------
extern "C" void kernel_launch(void* const* d_in, const int* in_sizes, int n_in,
                              void* d_out, int out_size, void* d_ws, size_t ws_size,
                              hipStream_t stream) {
  const void* image_embed     = d_in[0];
  const void* text_embed      = d_in[1];
  const int*  timesteps       = (const int*)d_in[2];
  const void* time_table      = d_in[3];
  const void* learned_query   = d_in[4];
  const void* rel_emb         = d_in[5];
  const void* attn_norm_g     = d_in[6];
  const void* Wq              = d_in[7];
  const void* Wkv             = d_in[8];
  const void* null_kv         = d_in[9];
  const void* Wo              = d_in[10];
  const void* attn_out_norm_g = d_in[11];
  const void* ff_norm_g       = d_in[12];
  const void* Wff1            = d_in[13];
  const void* Wff2            = d_in[14];
  const void* final_norm_g    = d_in[15];
  const void* Wproj           = d_in[16];

  if (ws_size < WS_NEED) return;

  char* ws = (char*)d_ws;
  __bf16* wqkv = (__bf16*)(ws + OFF_WQKV);
  __bf16* wto  = (__bf16*)(ws + OFF_WTO);
  __bf16* wtf1 = (__bf16*)(ws + OFF_WTF1);   // interleaved
  __bf16* wtf2 = (__bf16*)(ws + OFF_WTF2);
  __bf16* wtp  = (__bf16*)(ws + OFF_WTP);
  float*  x    = (float*) (ws + OFF_X);
  __bf16* h    = (__bf16*)(ws + OFF_H);
  __bf16* qkv  = (__bf16*)(ws + OFF_QKV);   // also y; FF act buffer starts here
  __bf16* ao   = (__bf16*)(ws + OFF_AO);    // attn_out / hlast
  __bf16* act  = (__bf16*)(ws + OFF_QKV);   // 16384 x 2048 bf16 (67MB)
  int*    flag = (int*)   (ws + OFF_FLAG);

  detect_dtype<<<1, 256, 0, stream>>>((const unsigned int*)Wq, flag);

  dim3 tb(32, 8);
  transpose_any<<<dim3(16, 16, 12),  tb, 0, stream>>>(Wq,   (u16*)wqkv, 512,  512,  640ull*512, 0,   0, flag);
  transpose_any<<<dim3(4,  16, 12),  tb, 0, stream>>>(Wkv,  (u16*)wqkv, 512,  128,  640ull*512, 512, 0, flag);
  transpose_any<<<dim3(16, 16, 12),  tb, 0, stream>>>(Wo,   (u16*)wto,  512,  512,  512ull*512, 0,   0, flag);
  transpose_any<<<dim3(128,16, 12),  tb, 0, stream>>>(Wff1, (u16*)wtf1, 512,  4096, 4096ull*512,0,   1, flag);
  transpose_any<<<dim3(16, 64, 12),  tb, 0, stream>>>(Wff2, (u16*)wtf2, 2048, 512,  512ull*2048,0,   0, flag);
  transpose_any<<<dim3(16, 16, 1),   tb, 0, stream>>>(Wproj,(u16*)wtp,  512,  512,  512ull*512, 0,   0, flag);

  build_tokens<<<BATCH, 256, 0, stream>>>(text_embed, image_embed, timesteps, time_table,
                                          learned_query, x, flag);

  for (int l = 0; l < DEPTH; l++) {
    const __bf16* wqkv_l = wqkv + (size_t)l * 640 * 512;
    const __bf16* wto_l  = wto  + (size_t)l * 512 * 512;
    const __bf16* wtf1_l = wtf1 + (size_t)l * 4096 * 512;
    const __bf16* wtf2_l = wtf2 + (size_t)l * 512 * 2048;

    // attention block
    ln_f32_bf16<<<ROWS/4, 256, 0, stream>>>(x, attn_norm_g, (size_t)l*DIM, h, flag);
    gemm4<0><<<dim3(5, 256), 256, 0, stream>>>(h, DIM, wqkv_l, 512, qkv, 640, 512, flag);
    attn_kernel<<<BATCH/2, 256, 0, stream>>>(qkv, null_kv, l, rel_emb, ao, flag);
    gemm4<0><<<dim3(4, 256), 256, 0, stream>>>(ao, DIM, wto_l, 512, qkv /*y*/, DIM, 512, flag);
    ln_add_ln<<<ROWS/4, 256, 0, stream>>>(qkv /*y*/, attn_out_norm_g, (size_t)l*DIM,
                                          ff_norm_g, (size_t)l*DIM, x, h, flag);

    // FF: two M-chunks of 16384 rows; act = 16384 x 2048 bf16
    for (int c = 0; c < 2; c++) {
      const __bf16* hc = h + (size_t)c * 16384 * DIM;
      float*        xc = x + (size_t)c * 16384 * DIM;
      gemm8<256,1><<<dim3(16, 64), 512, 0, stream>>>(hc, DIM, wtf1_l, 512, act, FFI, 512, flag);
      gemm4<2><<<dim3(4, 128), 256, 0, stream>>>(act, FFI, wtf2_l, FFI, xc, DIM, 2048, flag);
    }
  }

  ln_final<<<BATCH/4, 256, 0, stream>>>(x, final_norm_g, ao /*hlast*/, flag);
  gemm4<3><<<dim3(4, 64), 256, 0, stream>>>(ao, DIM, wtp, 512, d_out, DIM, 512, flag);
}

// Round 12
// 5683.124 us; speedup vs baseline: 1.0052x; 1.0052x over previous
//
#include <hip/hip_runtime.h>

typedef __bf16 bf16x8 __attribute__((ext_vector_type(8)));
typedef __bf16 bf16x4 __attribute__((ext_vector_type(4)));
typedef __bf16 bf16x2 __attribute__((ext_vector_type(2)));
typedef float  f32x4  __attribute__((ext_vector_type(4)));
typedef unsigned short u16;

// ---------------- constants ----------------
#define BATCH   8192
#define NTOK    4
#define ROWS    (BATCH*NTOK)      // 32768
#define DIM     512
#define HEADS   8
#define DH      64
#define FFI     2048              // FF_INNER
#define DEPTH   12
#define LN_EPS  1e-5f

// ---------------- workspace layout (bytes) ----------------
static const size_t OFF_WQKV = 0;                               // (12, 640, 512) bf16
static const size_t SZ_WQKV  = 12ull*640*512*2;
static const size_t OFF_WTO  = OFF_WQKV + SZ_WQKV;
static const size_t SZ_WTO   = 12ull*512*512*2;
static const size_t OFF_WTF1 = OFF_WTO + SZ_WTO;                // interleaved layout (12,4096,512)
static const size_t SZ_WTF1  = 12ull*4096*512*2;
static const size_t OFF_WTF2 = OFF_WTF1 + SZ_WTF1;
static const size_t SZ_WTF2  = 12ull*512*2048*2;
static const size_t OFF_WTP  = OFF_WTF2 + SZ_WTF2;
static const size_t SZ_WTP   = 512ull*512*2;
static const size_t OFF_X    = OFF_WTP + SZ_WTP;                // f32 (32768,512)
static const size_t OFF_H    = OFF_X    + (size_t)ROWS*DIM*4;
static const size_t OFF_QKV  = OFF_H    + (size_t)ROWS*DIM*2;   // (32768,640) bf16; also y; act[0:67MB)
static const size_t OFF_AO   = OFF_QKV  + (size_t)ROWS*640*2;   // attn_out / act cont'd / hlast
static const size_t OFF_FLAG = OFF_AO   + (size_t)ROWS*DIM*2;
static const size_t WS_NEED  = OFF_FLAG + 256;                  // ~266 MB
// FF act buffer (16384 x 2048 bf16 = 67,108,864 B) aliases [OFF_QKV, OFF_QKV+67MB):
// spans qkv(41.9M)+ao(33.5M) = 75.5MB of dead-after-attn space. OK.

// ---------------- helpers ----------------
__device__ __forceinline__ float ldf(const void* p, size_t i, bool b16) {
  return b16 ? (float)((const __bf16*)p)[i] : ((const float*)p)[i];
}

__device__ __forceinline__ void gld_lds16(const void* g, void* l) {
  __builtin_amdgcn_global_load_lds((const __attribute__((address_space(1))) void*)g,
                                   (__attribute__((address_space(3))) void*)l, 16, 0, 0);
}

// 16-lane-group sum (xor butterfly, offsets 8..1 stay within the group)
__device__ __forceinline__ float gsum16(float v) {
  #pragma unroll
  for (int o = 8; o > 0; o >>= 1) v += __shfl_xor(v, o, 64);
  return v;
}

// full-wave reduce of a pair
__device__ __forceinline__ void wred2(float& a, float& b) {
  #pragma unroll
  for (int o = 32; o > 0; o >>= 1) { a += __shfl_xor(a, o, 64); b += __shfl_xor(b, o, 64); }
}

// ---------------- dtype detection: 1 block, writes flag (1 = bf16, 0 = fp32) ----------------
__global__ void detect_dtype(const unsigned int* __restrict__ w, int* __restrict__ flag) {
  __shared__ int cnt[4];
  int t = threadIdx.x;
  int c = 0;
  for (int i = t; i < 2048; i += 256) {
    unsigned int v = w[i];
    unsigned int lo = v & 0xFFFFu, hi = v >> 16;
    int elo = (int)((lo >> 7) & 0xFF), ehi = (int)((hi >> 7) & 0xFF);
    bool okl = (lo == 0u) || (elo >= 100 && elo <= 140);
    bool okh = (hi == 0u) || (ehi >= 100 && ehi <= 140);
    if (okl && okh) c++;
  }
  #pragma unroll
  for (int o = 32; o > 0; o >>= 1) c += __shfl_down(c, o, 64);
  if ((t & 63) == 0) cnt[t >> 6] = c;
  __syncthreads();
  if (t == 0) flag[0] = (cnt[0] + cnt[1] + cnt[2] + cnt[3] > 1024) ? 1 : 0;
}

// ---------------- weight transpose (K,N)->(N,K), optional ff1 interleave ----------------
__global__ void transpose_any(const void* __restrict__ in, u16* __restrict__ out,
                              int K, int N, size_t out_zsz, int rowoff, int mode,
                              const int* __restrict__ flag) {
  bool b16 = flag[0] != 0;
  __shared__ u16 tile[32][33];
  size_t iboff = (size_t)blockIdx.z * K * N;
  size_t oboff = (size_t)blockIdx.z * out_zsz;
  int n0 = blockIdx.x * 32, k0 = blockIdx.y * 32;
  int tx = threadIdx.x, ty = threadIdx.y;
  #pragma unroll
  for (int r = 0; r < 4; r++) {
    float v = ldf(in, iboff + (size_t)(k0 + ty*4 + r) * N + n0 + tx, b16);
    __bf16 bv = (__bf16)v;
    tile[ty*4+r][tx] = __builtin_bit_cast(u16, bv);
  }
  __syncthreads();
  int rbase;
  if (mode == 0) rbase = rowoff + n0;
  else {
    int s = (n0 >= 2048) ? 1 : 0;
    int np = n0 - s*2048;
    rbase = (np >> 7)*256 + ((np >> 5) & 3)*64 + s*32;   // n0 % 32 == 0
  }
  #pragma unroll
  for (int r = 0; r < 4; r++)
    out[oboff + (size_t)(rbase + ty*4 + r) * K + k0 + tx] = tile[tx][ty*4+r];
}

// ---------------- token assembly: x (B,4,512) f32 ----------------
__global__ void build_tokens(const void* __restrict__ text, const void* __restrict__ img,
                             const int* __restrict__ ts, const void* __restrict__ table,
                             const void* __restrict__ lq, float* __restrict__ x,
                             const int* __restrict__ flag) {
  bool b16 = flag[0] != 0;
  int b = blockIdx.x, t = threadIdx.x;
  float* xr = x + (size_t)b * NTOK * DIM;
  int tsb = ts[b];
  for (int e = t; e < DIM; e += 256) {
    xr[e]         = ldf(text,  (size_t)b * DIM + e, b16);
    xr[DIM + e]   = ldf(table, (size_t)tsb * DIM + e, b16);
    xr[2*DIM + e] = ldf(img,   (size_t)b * DIM + e, b16);
    xr[3*DIM + e] = ldf(lq,    (size_t)e, b16);
  }
}

// ---------------- LN: f32 row -> bf16 row (wave-per-row) ----------------
__global__ void ln_f32_bf16(const float* __restrict__ x, const void* __restrict__ g, size_t goff,
                            __bf16* __restrict__ out, const int* __restrict__ flag) {
  bool b16 = flag[0] != 0;
  int lane = threadIdx.x & 63;
  int row = blockIdx.x * 4 + (threadIdx.x >> 6);
  const float4* xr = (const float4*)(x + (size_t)row * DIM);
  float4 A4 = xr[lane*2], B4 = xr[lane*2 + 1];
  float v[8] = {A4.x, A4.y, A4.z, A4.w, B4.x, B4.y, B4.z, B4.w};
  float s = 0.f, s2 = 0.f;
  #pragma unroll
  for (int e = 0; e < 8; e++) { s += v[e]; s2 += v[e]*v[e]; }
  wred2(s, s2);
  float mean = s * (1.f/DIM);
  float var  = s2 * (1.f/DIM) - mean*mean;
  float rs = rsqrtf(var + LN_EPS);
  bf16x8 ov;
  #pragma unroll
  for (int e = 0; e < 8; e++)
    ov[e] = (__bf16)((v[e]-mean) * rs * ldf(g, goff + lane*8 + e, b16));
  *(bf16x8*)(out + (size_t)row * DIM + lane*8) = ov;
}

// ---------------- fused: x += LN(y; g1); h = LN(x; g2) (wave-per-row) ----------------
__global__ void ln_add_ln(const __bf16* __restrict__ y,
                          const void* __restrict__ g1, size_t g1off,
                          const void* __restrict__ g2, size_t g2off,
                          float* __restrict__ x, __bf16* __restrict__ h,
                          const int* __restrict__ flag) {
  bool b16 = flag[0] != 0;
  int lane = threadIdx.x & 63;
  int row = blockIdx.x * 4 + (threadIdx.x >> 6);
  bf16x8 y8 = *(const bf16x8*)(y + (size_t)row * DIM + lane*8);
  float yv[8];
  float s = 0.f, s2 = 0.f;
  #pragma unroll
  for (int e = 0; e < 8; e++) { yv[e] = (float)y8[e]; s += yv[e]; s2 += yv[e]*yv[e]; }
  wred2(s, s2);
  float mean = s * (1.f/DIM);
  float var  = s2 * (1.f/DIM) - mean*mean;
  float rs = rsqrtf(var + LN_EPS);
  float4* xr = (float4*)(x + (size_t)row * DIM);
  float4 XA = xr[lane*2], XB = xr[lane*2 + 1];
  float xv[8] = {XA.x, XA.y, XA.z, XA.w, XB.x, XB.y, XB.z, XB.w};
  #pragma unroll
  for (int e = 0; e < 8; e++)
    xv[e] += (yv[e]-mean) * rs * ldf(g1, g1off + lane*8 + e, b16);
  xr[lane*2]     = make_float4(xv[0], xv[1], xv[2], xv[3]);
  xr[lane*2 + 1] = make_float4(xv[4], xv[5], xv[6], xv[7]);
  float t = 0.f, t2 = 0.f;
  #pragma unroll
  for (int e = 0; e < 8; e++) { t += xv[e]; t2 += xv[e]*xv[e]; }
  wred2(t, t2);
  float mean2 = t * (1.f/DIM);
  float var2  = t2 * (1.f/DIM) - mean2*mean2;
  float rs2 = rsqrtf(var2 + LN_EPS);
  bf16x8 hv;
  #pragma unroll
  for (int e = 0; e < 8; e++)
    hv[e] = (__bf16)((xv[e]-mean2) * rs2 * ldf(g2, g2off + lane*8 + e, b16));
  *(bf16x8*)(h + (size_t)row * DIM + lane*8) = hv;
}

// ---------------- final LN on token-3 rows -> hlast (8192,512) bf16 (wave-per-b) ----------------
__global__ void ln_final(const float* __restrict__ x, const void* __restrict__ g,
                         __bf16* __restrict__ out, const int* __restrict__ flag) {
  bool b16 = flag[0] != 0;
  int lane = threadIdx.x & 63;
  int b = blockIdx.x * 4 + (threadIdx.x >> 6);
  int row = b*NTOK + 3;
  const float4* xr = (const float4*)(x + (size_t)row * DIM);
  float4 A4 = xr[lane*2], B4 = xr[lane*2 + 1];
  float v[8] = {A4.x, A4.y, A4.z, A4.w, B4.x, B4.y, B4.z, B4.w};
  float s = 0.f, s2 = 0.f;
  #pragma unroll
  for (int e = 0; e < 8; e++) { s += v[e]; s2 += v[e]*v[e]; }
  wred2(s, s2);
  float mean = s * (1.f/DIM);
  float var  = s2 * (1.f/DIM) - mean*mean;
  float rs = rsqrtf(var + LN_EPS);
  bf16x8 ov;
  #pragma unroll
  for (int e = 0; e < 8; e++)
    ov[e] = (__bf16)((v[e]-mean) * rs * ldf(g, (size_t)lane*8 + e, b16));
  *(bf16x8*)(out + (size_t)b * DIM + lane*8) = ov;
}

// ================= gemm8: EXACT r6 config (hfl schedule). Proven best; do not perturb. ====
// EPI 0: bf16; EPI 2: f32 +=; EPI 3: per-flag.
template<int BROWS, int EPI>
__global__ __launch_bounds__(512, 2) void gemm8(
    const __bf16* __restrict__ A, int lda,
    const __bf16* __restrict__ B, int ldb,
    void* __restrict__ Cv, int ldc, int K, const int* __restrict__ flag)
{
  constexpr int UNITS = (BROWS == 256) ? 4 : 3;
  constexpr int WCN   = (BROWS == 256) ? 4 : 2;
  constexpr int M_FR  = (BROWS == 256) ? 8 : 4;
  constexpr int QM    = M_FR / 4;
  __shared__ char ldsmem[2][(256 + BROWS) * 128];

  const int tid = threadIdx.x;
  const int wid = tid >> 6, lane = tid & 63;
  const int wr = wid / WCN, wc = wid % WCN;
  const int lr = lane & 15, lc = lane >> 4;
  const int sr = tid >> 3;
  const int cs = ((tid & 7) ^ (sr & 7)) * 8;
  const int bx = blockIdx.x, by = blockIdx.y;

  const __bf16* Ab = A + (size_t)by * 256 * lda;
  const __bf16* Bb = B + (size_t)bx * BROWS * ldb;

  f32x4 acc[M_FR][4] = {};
  const int NT = K >> 6;

  char* lds0 = ldsmem[0];
  char* lds1 = ldsmem[1];

  auto stage_unit = [&](int p, int kt, int u) {
    char* base = (p ? lds1 : lds0);
    if (u < 2) {
      const __bf16* s = Ab + (size_t)(u*128 + sr) * lda + kt*64 + cs;
      char* d = base + u*16384 + (wid << 10);
      gld_lds16(s, d);
      gld_lds16(s + (size_t)64 * lda, d + 8192);
    } else {
      const __bf16* s = Bb + (size_t)((u-2)*128 + sr) * ldb + kt*64 + cs;
      char* d = base + 32768 + (u-2)*16384 + (wid << 10);
      gld_lds16(s, d);
      gld_lds16(s + (size_t)64 * ldb, d + 8192);
    }
  };

  #pragma unroll
  for (int u = 0; u < UNITS; u++) stage_unit(0, 0, u);

  const int NIT = NT >> 1;
  for (int i = 0; i < NIT; i++) {
    const int t1 = 2*i + 1;
    const int t2 = (2*i + 2 < NT) ? (2*i + 2) : 0;
    #pragma unroll
    for (int hfl = 0; hfl < 2; hfl++) {
      char* cbase = hfl ? lds1 : lds0;
      const int sp = hfl ^ 1;
      const int st = hfl ? t2 : t1;
      bf16x8 bfr[4][2];
      #pragma unroll
      for (int q = 0; q < 4; q++) {
        if (q < UNITS) stage_unit(sp, st, q);
        if (q == 0) {
          asm volatile("s_waitcnt vmcnt(2)" ::: "memory");
          asm volatile("s_barrier" ::: "memory");
          #pragma unroll
          for (int f = 0; f < 4; f++)
            #pragma unroll
            for (int kk = 0; kk < 2; kk++) {
              int row = wc*64 + f*16 + lr;
              int ch = (kk*4 + lc) ^ (lr & 7);
              bfr[f][kk] = *(const bf16x8*)(cbase + 32768 + row*128 + ch*16);
            }
        }
        bf16x8 afr[QM][2];
        #pragma unroll
        for (int m2 = 0; m2 < QM; m2++)
          #pragma unroll
          for (int kk = 0; kk < 2; kk++) {
            int row = wr*(M_FR*16) + (q*QM + m2)*16 + lr;
            int ch = (kk*4 + lc) ^ (lr & 7);
            afr[m2][kk] = *(const bf16x8*)(cbase + row*128 + ch*16);
          }
        __builtin_amdgcn_s_setprio(1);
        #pragma unroll
        for (int m2 = 0; m2 < QM; m2++)
          #pragma unroll
          for (int n = 0; n < 4; n++)
            #pragma unroll
            for (int kk = 0; kk < 2; kk++)
              acc[q*QM + m2][n] = __builtin_amdgcn_mfma_f32_16x16x32_bf16(
                  afr[m2][kk], bfr[n][kk], acc[q*QM + m2][n], 0, 0, 0);
        __builtin_amdgcn_s_setprio(0);
        asm volatile("s_barrier" ::: "memory");
      }
    }
  }
  asm volatile("s_waitcnt vmcnt(0)" ::: "memory");  // drain dummy staging

  if (EPI == 2) {
    float* Xf = (float*)Cv;
    const int colb = bx*BROWS + wc*64 + lr;
    const int rowb = by*256 + wr*(M_FR*16) + lc*4;
    #pragma unroll
    for (int m = 0; m < M_FR; m++)
      #pragma unroll
      for (int rr = 0; rr < 4; rr++) {
        size_t ro = (size_t)(rowb + m*16 + rr) * ldc;
        #pragma unroll
        for (int n = 0; n < 4; n++) Xf[ro + colb + n*16] += acc[m][n][rr];
      }
  } else if (EPI == 0) {
    __bf16* Cb = (__bf16*)Cv;
    const int colb = bx*BROWS + wc*64 + lr;
    const int rowb = by*256 + wr*(M_FR*16) + lc*4;
    #pragma unroll
    for (int m = 0; m < M_FR; m++)
      #pragma unroll
      for (int rr = 0; rr < 4; rr++) {
        size_t ro = (size_t)(rowb + m*16 + rr) * ldc;
        #pragma unroll
        for (int n = 0; n < 4; n++) Cb[ro + colb + n*16] = (__bf16)acc[m][n][rr];
      }
  } else {
    bool b16o = flag[0] != 0;
    __bf16* Cb = (__bf16*)Cv;
    float*  Cf = (float*)Cv;
    const int colb = bx*BROWS + wc*64 + lr;
    const int rowb = by*256 + wr*(M_FR*16) + lc*4;
    #pragma unroll
    for (int m = 0; m < M_FR; m++)
      #pragma unroll
      for (int rr = 0; rr < 4; rr++) {
        size_t ro = (size_t)(rowb + m*16 + rr) * ldc;
        #pragma unroll
        for (int n = 0; n < 4; n++) {
          float val = acc[m][n][rr];
          if (b16o) Cb[ro + colb + n*16] = (__bf16)val; else Cf[ro + colb + n*16] = val;
        }
      }
  }
}

// ================= gemm8p: PERSISTENT swiglu (r6 schedule, 4 output tiles per block) =====
// Grid 256 = 1 block/CU. Block p owns bx = p&15 (B-panel reuse across its 4 tiles),
// by = (p>>4)*4 + j for j=0..3. The last K-tile's dummy re-stage slot becomes the REAL
// prologue of tile j+1 (same buffer parity: t=NT-1 stages into buf0 = next tile's t=0
// compute buffer). Epilogue (register-only) overlaps the in-flight staging; ordering is
// provided by the next tile's vmcnt(2)+barrier at q0. K-loop schedule byte-identical to r6.
__global__ __launch_bounds__(512, 2) void gemm8p(
    const __bf16* __restrict__ A, int lda,
    const __bf16* __restrict__ B, int ldb,
    __bf16* __restrict__ Out, int ldc, int K)
{
  constexpr int M_FR = 8;
  constexpr int QM   = 2;
  __shared__ char ldsmem[2][512 * 128];

  const int tid = threadIdx.x;
  const int wid = tid >> 6, lane = tid & 63;
  const int wr = wid >> 2, wc = wid & 3;
  const int lr = lane & 15, lc = lane >> 4;
  const int sr = tid >> 3;
  const int cs = ((tid & 7) ^ (sr & 7)) * 8;
  const int bx = blockIdx.x & 15;
  const int by0 = (blockIdx.x >> 4) * 4;

  const __bf16* Bb = B + (size_t)bx * 256 * ldb;
  const int NT = K >> 6;       // 8
  const int NIT = NT >> 1;

  char* lds0 = ldsmem[0];
  char* lds1 = ldsmem[1];

  // stage one 128-row unit of K-tile kt into buffer p. u: 0,1 = A halves; 2,3 = B halves.
  auto stage_unit = [&](const __bf16* Ab, int p, int kt, int u) {
    char* base = (p ? lds1 : lds0);
    if (u < 2) {
      const __bf16* s = Ab + (size_t)(u*128 + sr) * lda + kt*64 + cs;
      char* d = base + u*16384 + (wid << 10);
      gld_lds16(s, d);
      gld_lds16(s + (size_t)64 * lda, d + 8192);
    } else {
      const __bf16* s = Bb + (size_t)((u-2)*128 + sr) * ldb + kt*64 + cs;
      char* d = base + 32768 + (u-2)*16384 + (wid << 10);
      gld_lds16(s, d);
      gld_lds16(s + (size_t)64 * ldb, d + 8192);
    }
  };

  const __bf16* Ab = A + (size_t)by0 * 256 * lda;
  #pragma unroll
  for (int u = 0; u < 4; u++) stage_unit(Ab, 0, 0, u);

  for (int j = 0; j < 4; j++) {
    const __bf16* Ab_nxt = A + (size_t)(by0 + ((j+1) & 3)) * 256 * lda;
    f32x4 acc[M_FR][4] = {};
    for (int i = 0; i < NIT; i++) {
      const int t1 = 2*i + 1;
      const bool last = (2*i + 2 >= NT);
      const int t2 = last ? 0 : (2*i + 2);
      #pragma unroll
      for (int hfl = 0; hfl < 2; hfl++) {
        char* cbase = hfl ? lds1 : lds0;
        const int sp = hfl ^ 1;
        const int st = hfl ? t2 : t1;
        const __bf16* Asrc = (hfl && last) ? Ab_nxt : Ab;   // last slot = next tile's prologue
        bf16x8 bfr[4][2];
        #pragma unroll
        for (int q = 0; q < 4; q++) {
          stage_unit(Asrc, sp, st, q);
          if (q == 0) {
            asm volatile("s_waitcnt vmcnt(2)" ::: "memory");
            asm volatile("s_barrier" ::: "memory");
            #pragma unroll
            for (int f = 0; f < 4; f++)
              #pragma unroll
              for (int kk = 0; kk < 2; kk++) {
                int row = wc*64 + f*16 + lr;
                int ch = (kk*4 + lc) ^ (lr & 7);
                bfr[f][kk] = *(const bf16x8*)(cbase + 32768 + row*128 + ch*16);
              }
          }
          bf16x8 afr[QM][2];
          #pragma unroll
          for (int m2 = 0; m2 < QM; m2++)
            #pragma unroll
            for (int kk = 0; kk < 2; kk++) {
              int row = wr*128 + (q*QM + m2)*16 + lr;
              int ch = (kk*4 + lc) ^ (lr & 7);
              afr[m2][kk] = *(const bf16x8*)(cbase + row*128 + ch*16);
            }
          __builtin_amdgcn_s_setprio(1);
          #pragma unroll
          for (int m2 = 0; m2 < QM; m2++)
            #pragma unroll
            for (int n = 0; n < 4; n++)
              #pragma unroll
              for (int kk = 0; kk < 2; kk++)
                acc[q*QM + m2][n] = __builtin_amdgcn_mfma_f32_16x16x32_bf16(
                    afr[m2][kk], bfr[n][kk], acc[q*QM + m2][n], 0, 0, 0);
          __builtin_amdgcn_s_setprio(0);
          asm volatile("s_barrier" ::: "memory");
        }
      }
    }
    // epilogue: register-only swiglu; next tile's staging stays in flight.
    {
      const int colb = bx*128 + wc*32 + lr;
      const int rowb = (by0 + j)*256 + wr*128 + lc*4;
      #pragma unroll
      for (int m = 0; m < M_FR; m++)
        #pragma unroll
        for (int rr = 0; rr < 4; rr++) {
          size_t ro = (size_t)(rowb + m*16 + rr) * ldc;
          #pragma unroll
          for (int fa = 0; fa < 2; fa++) {
            float a = acc[m][fa][rr], g = acc[m][fa+2][rr];
            Out[ro + colb + fa*16] = (__bf16)(a * g / (1.f + __expf(-g)));
          }
        }
    }
    Ab = Ab_nxt;
  }
  asm volatile("s_waitcnt vmcnt(0)" ::: "memory");  // drain final dummy staging
}

// ---------------- fused attention, 16-lane-group layout ----------------
__global__ __launch_bounds__(256) void attn_kernel(
    const __bf16* __restrict__ qkv,
    const void* __restrict__ nkv_all, int layer, const void* __restrict__ rel_emb,
    __bf16* __restrict__ ao, const int* __restrict__ flag)
{
  bool b16 = flag[0] != 0;
  const int tid = threadIdx.x;
  const int w = tid >> 6, l = tid & 63;
  const int g = l >> 4, c = l & 15;
  const int bh = blockIdx.x * 16 + w * 4 + g;
  const int b = bh >> 3, h = bh & 7;
  const bool rot = (c < 8);   // d = 4c..4c+3 < 32

  const float LN1E4_32 = 9.210340371976184f * (1.f/32.f);
  float inv0 = __expf(-(float)(4*c)     * LN1E4_32);
  float inv1 = __expf(-(float)(4*c + 2) * LN1E4_32);
  float cs0[4], sn0[4], cs1[4], sn1[4];
  #pragma unroll
  for (int t = 0; t < 4; t++) {
    __sincosf((float)t * inv0, &sn0[t], &cs0[t]);
    __sincosf((float)t * inv1, &sn1[t], &cs1[t]);
  }
  float rb[4];
  #pragma unroll
  for (int t = 0; t < 4; t++) rb[t] = ldf(rel_emb, (size_t)t * 8 + h, b16);

  float q[4][4];
  #pragma unroll
  for (int i = 0; i < 4; i++) {
    bf16x4 qv = *(const bf16x4*)(qkv + ((size_t)(b*NTOK + i)) * 640 + h*DH + c*4);
    float v0 = (float)qv[0], v1 = (float)qv[1], v2 = (float)qv[2], v3 = (float)qv[3];
    if (rot) {
      float n0 = v0*cs0[i] - v1*sn0[i], n1 = v1*cs0[i] + v0*sn0[i];
      float n2 = v2*cs1[i] - v3*sn1[i], n3 = v3*cs1[i] + v2*sn1[i];
      v0 = n0; v1 = n1; v2 = n2; v3 = n3;
    }
    q[i][0] = v0; q[i][1] = v1; q[i][2] = v2; q[i][3] = v3;
  }
  #pragma unroll
  for (int i = 0; i < 4; i++) {
    float ss = q[i][0]*q[i][0] + q[i][1]*q[i][1] + q[i][2]*q[i][2] + q[i][3]*q[i][3];
    float r = 1.f / fmaxf(sqrtf(gsum16(ss)), 1e-12f);
    #pragma unroll
    for (int e = 0; e < 4; e++) q[i][e] *= r;
  }

  float kk[5][4], vv[5][4];
  #pragma unroll
  for (int e = 0; e < 4; e++) {
    kk[0][e] = ldf(nkv_all, (size_t)layer*128 + c*4 + e, b16);
    vv[0][e] = ldf(nkv_all, (size_t)layer*128 + 64 + c*4 + e, b16);
  }
  #pragma unroll
  for (int j = 1; j < 5; j++) {
    const __bf16* base = qkv + ((size_t)(b*NTOK + j - 1)) * 640 + 512;
    bf16x4 kv4 = *(const bf16x4*)(base + c*4);
    bf16x4 vv4 = *(const bf16x4*)(base + 64 + c*4);
    float v0 = (float)kv4[0], v1 = (float)kv4[1], v2 = (float)kv4[2], v3 = (float)kv4[3];
    if (rot) {
      int t = j - 1;
      float n0 = v0*cs0[t] - v1*sn0[t], n1 = v1*cs0[t] + v0*sn0[t];
      float n2 = v2*cs1[t] - v3*sn1[t], n3 = v3*cs1[t] + v2*sn1[t];
      v0 = n0; v1 = n1; v2 = n2; v3 = n3;
    }
    kk[j][0] = v0; kk[j][1] = v1; kk[j][2] = v2; kk[j][3] = v3;
    #pragma unroll
    for (int e = 0; e < 4; e++) vv[j][e] = (float)vv4[e];
  }
  #pragma unroll
  for (int j = 0; j < 5; j++) {
    float ss = kk[j][0]*kk[j][0] + kk[j][1]*kk[j][1] + kk[j][2]*kk[j][2] + kk[j][3]*kk[j][3];
    float r = 1.f / fmaxf(sqrtf(gsum16(ss)), 1e-12f);
    #pragma unroll
    for (int e = 0; e < 4; e++) kk[j][e] *= r;
  }

  #pragma unroll
  for (int i = 0; i < 4; i++) {
    float sim[5];
    #pragma unroll
    for (int j = 0; j < 5; j++) {
      if (j > i + 1) break;
      float pp = q[i][0]*kk[j][0] + q[i][1]*kk[j][1] + q[i][2]*kk[j][2] + q[i][3]*kk[j][3];
      sim[j] = 16.f * gsum16(pp) + rb[(i - j > 0) ? (i - j) : 0];
    }
    float m = sim[0];
    #pragma unroll
    for (int j = 1; j < 5; j++) { if (j > i + 1) break; m = fmaxf(m, sim[j]); }
    float Z = 0.f, o0 = 0.f, o1 = 0.f, o2 = 0.f, o3 = 0.f;
    #pragma unroll
    for (int j = 0; j < 5; j++) {
      if (j > i + 1) break;
      float e = __expf(sim[j] - m);
      Z += e;
      o0 += e * vv[j][0]; o1 += e * vv[j][1]; o2 += e * vv[j][2]; o3 += e * vv[j][3];
    }
    float rz = 1.f / Z;
    bf16x4 ov = { (__bf16)(o0*rz), (__bf16)(o1*rz), (__bf16)(o2*rz), (__bf16)(o3*rz) };
    *(bf16x4*)(ao + ((size_t)(b*NTOK + i)) * DIM + h*DH + c*4) = ov;
  }
}

// ---------------- launch ----------------
extern "C" void kernel_launch(void* const* d_in, const int* in_sizes, int n_in,
                              void* d_out, int out_size, void* d_ws, size_t ws_size,
                              hipStream_t stream) {
  const void* image_embed     = d_in[0];
  const void* text_embed      = d_in[1];
  const int*  timesteps       = (const int*)d_in[2];
  const void* time_table      = d_in[3];
  const void* learned_query   = d_in[4];
  const void* rel_emb         = d_in[5];
  const void* attn_norm_g     = d_in[6];
  const void* Wq              = d_in[7];
  const void* Wkv             = d_in[8];
  const void* null_kv         = d_in[9];
  const void* Wo              = d_in[10];
  const void* attn_out_norm_g = d_in[11];
  const void* ff_norm_g       = d_in[12];
  const void* Wff1            = d_in[13];
  const void* Wff2            = d_in[14];
  const void* final_norm_g    = d_in[15];
  const void* Wproj           = d_in[16];

  if (ws_size < WS_NEED) return;

  char* ws = (char*)d_ws;
  __bf16* wqkv = (__bf16*)(ws + OFF_WQKV);
  __bf16* wto  = (__bf16*)(ws + OFF_WTO);
  __bf16* wtf1 = (__bf16*)(ws + OFF_WTF1);   // interleaved
  __bf16* wtf2 = (__bf16*)(ws + OFF_WTF2);
  __bf16* wtp  = (__bf16*)(ws + OFF_WTP);
  float*  x    = (float*) (ws + OFF_X);
  __bf16* h    = (__bf16*)(ws + OFF_H);
  __bf16* qkv  = (__bf16*)(ws + OFF_QKV);   // also y; FF act buffer starts here
  __bf16* ao   = (__bf16*)(ws + OFF_AO);    // attn_out / hlast
  __bf16* act  = (__bf16*)(ws + OFF_QKV);   // 16384 x 2048 bf16 (67MB)
  int*    flag = (int*)   (ws + OFF_FLAG);

  detect_dtype<<<1, 256, 0, stream>>>((const unsigned int*)Wq, flag);

  dim3 tb(32, 8);
  transpose_any<<<dim3(16, 16, 12),  tb, 0, stream>>>(Wq,   (u16*)wqkv, 512,  512,  640ull*512, 0,   0, flag);
  transpose_any<<<dim3(4,  16, 12),  tb, 0, stream>>>(Wkv,  (u16*)wqkv, 512,  128,  640ull*512, 512, 0, flag);
  transpose_any<<<dim3(16, 16, 12),  tb, 0, stream>>>(Wo,   (u16*)wto,  512,  512,  512ull*512, 0,   0, flag);
  transpose_any<<<dim3(128,16, 12),  tb, 0, stream>>>(Wff1, (u16*)wtf1, 512,  4096, 4096ull*512,0,   1, flag);
  transpose_any<<<dim3(16, 64, 12),  tb, 0, stream>>>(Wff2, (u16*)wtf2, 2048, 512,  512ull*2048,0,   0, flag);
  transpose_any<<<dim3(16, 16, 1),   tb, 0, stream>>>(Wproj,(u16*)wtp,  512,  512,  512ull*512, 0,   0, flag);

  build_tokens<<<BATCH, 256, 0, stream>>>(text_embed, image_embed, timesteps, time_table,
                                          learned_query, x, flag);

  for (int l = 0; l < DEPTH; l++) {
    const __bf16* wqkv_l = wqkv + (size_t)l * 640 * 512;
    const __bf16* wto_l  = wto  + (size_t)l * 512 * 512;
    const __bf16* wtf1_l = wtf1 + (size_t)l * 4096 * 512;
    const __bf16* wtf2_l = wtf2 + (size_t)l * 512 * 2048;

    // attention block
    ln_f32_bf16<<<ROWS/4, 256, 0, stream>>>(x, attn_norm_g, (size_t)l*DIM, h, flag);
    gemm8<128,0><<<dim3(5, 128), 512, 0, stream>>>(h, DIM, wqkv_l, 512, qkv, 640, 512, flag);
    attn_kernel<<<BATCH/2, 256, 0, stream>>>(qkv, null_kv, l, rel_emb, ao, flag);
    gemm8<128,0><<<dim3(4, 128), 512, 0, stream>>>(ao, DIM, wto_l, 512, qkv /*y*/, DIM, 512, flag);
    ln_add_ln<<<ROWS/4, 256, 0, stream>>>(qkv /*y*/, attn_out_norm_g, (size_t)l*DIM,
                                          ff_norm_g, (size_t)l*DIM, x, h, flag);

    // FF: two M-chunks of 16384 rows; act = 16384 x 2048 bf16
    for (int c = 0; c < 2; c++) {
      const __bf16* hc = h + (size_t)c * 16384 * DIM;
      float*        xc = x + (size_t)c * 16384 * DIM;
      gemm8p<<<256, 512, 0, stream>>>(hc, DIM, wtf1_l, 512, act, FFI, 512);
      gemm8<128,2><<<dim3(4, 64), 512, 0, stream>>>(act, FFI, wtf2_l, FFI, xc, DIM, 2048, flag);
    }
  }

  ln_final<<<BATCH/4, 256, 0, stream>>>(x, final_norm_g, ao /*hlast*/, flag);
  gemm8<128,3><<<dim3(4, 32), 512, 0, stream>>>(ao, DIM, wtp, 512, d_out, DIM, 512, flag);
}

// Round 13
// 5381.598 us; speedup vs baseline: 1.0616x; 1.0560x over previous
//
#include <hip/hip_runtime.h>

typedef __bf16 bf16x8 __attribute__((ext_vector_type(8)));
typedef __bf16 bf16x4 __attribute__((ext_vector_type(4)));
typedef __bf16 bf16x2 __attribute__((ext_vector_type(2)));
typedef float  f32x4  __attribute__((ext_vector_type(4)));
typedef unsigned short u16;

// ---------------- constants ----------------
#define BATCH   8192
#define NTOK    4
#define ROWS    (BATCH*NTOK)      // 32768
#define DIM     512
#define HEADS   8
#define DH      64
#define FFI     2048              // FF_INNER
#define DEPTH   12
#define LN_EPS  1e-5f

// ---------------- workspace layout (bytes) ----------------
static const size_t OFF_WQKV = 0;                               // (12, 640, 512) bf16
static const size_t SZ_WQKV  = 12ull*640*512*2;
static const size_t OFF_WTO  = OFF_WQKV + SZ_WQKV;
static const size_t SZ_WTO   = 12ull*512*512*2;
static const size_t OFF_WTF1 = OFF_WTO + SZ_WTO;                // interleaved layout (12,4096,512)
static const size_t SZ_WTF1  = 12ull*4096*512*2;
static const size_t OFF_WTF2 = OFF_WTF1 + SZ_WTF1;
static const size_t SZ_WTF2  = 12ull*512*2048*2;
static const size_t OFF_WTP  = OFF_WTF2 + SZ_WTF2;
static const size_t SZ_WTP   = 512ull*512*2;
static const size_t OFF_X    = OFF_WTP + SZ_WTP;                // f32 (32768,512)
static const size_t OFF_H    = OFF_X    + (size_t)ROWS*DIM*4;
static const size_t OFF_QKV  = OFF_H    + (size_t)ROWS*DIM*2;   // (32768,640) bf16; also y; act[0:67MB)
static const size_t OFF_AO   = OFF_QKV  + (size_t)ROWS*640*2;   // attn_out / act cont'd / hlast
static const size_t OFF_FLAG = OFF_AO   + (size_t)ROWS*DIM*2;
static const size_t WS_NEED  = OFF_FLAG + 256;                  // ~266 MB
// FF act buffer (16384 x 2048 bf16 = 67,108,864 B) aliases [OFF_QKV, OFF_QKV+67MB):
// spans qkv(41.9M)+ao(33.5M) = 75.5MB of dead-after-attn space. OK.

// ---------------- helpers ----------------
__device__ __forceinline__ float ldf(const void* p, size_t i, bool b16) {
  return b16 ? (float)((const __bf16*)p)[i] : ((const float*)p)[i];
}

__device__ __forceinline__ void gld_lds16(const void* g, void* l) {
  __builtin_amdgcn_global_load_lds((const __attribute__((address_space(1))) void*)g,
                                   (__attribute__((address_space(3))) void*)l, 16, 0, 0);
}

// 16-lane-group sum (xor butterfly, offsets 8..1 stay within the group)
__device__ __forceinline__ float gsum16(float v) {
  #pragma unroll
  for (int o = 8; o > 0; o >>= 1) v += __shfl_xor(v, o, 64);
  return v;
}

// 256-thread block reduce of (a,b); barrier-balanced so it is safe to call twice
__device__ __forceinline__ void block_reduce2(float& a, float& b, float* sm) {
  #pragma unroll
  for (int o = 32; o > 0; o >>= 1) { a += __shfl_down(a, o, 64); b += __shfl_down(b, o, 64); }
  int lane = threadIdx.x & 63, w = threadIdx.x >> 6;
  __syncthreads();
  if (lane == 0) { sm[w] = a; sm[4+w] = b; }
  __syncthreads();
  a = sm[0]+sm[1]+sm[2]+sm[3];
  b = sm[4]+sm[5]+sm[6]+sm[7];
}

// ---------------- dtype detection: 1 block, writes flag (1 = bf16, 0 = fp32) ----------------
__global__ void detect_dtype(const unsigned int* __restrict__ w, int* __restrict__ flag) {
  __shared__ int cnt[4];
  int t = threadIdx.x;
  int c = 0;
  for (int i = t; i < 2048; i += 256) {
    unsigned int v = w[i];
    unsigned int lo = v & 0xFFFFu, hi = v >> 16;
    int elo = (int)((lo >> 7) & 0xFF), ehi = (int)((hi >> 7) & 0xFF);
    bool okl = (lo == 0u) || (elo >= 100 && elo <= 140);
    bool okh = (hi == 0u) || (ehi >= 100 && ehi <= 140);
    if (okl && okh) c++;
  }
  #pragma unroll
  for (int o = 32; o > 0; o >>= 1) c += __shfl_down(c, o, 64);
  if ((t & 63) == 0) cnt[t >> 6] = c;
  __syncthreads();
  if (t == 0) flag[0] = (cnt[0] + cnt[1] + cnt[2] + cnt[3] > 1024) ? 1 : 0;
}

// ---------------- weight transpose (K,N)->(N,K), optional ff1 interleave ----------------
// mode 0: out row = rowoff + n.  mode 1: swiglu interleave row mapping:
//   n -> s=(n>=2048), n'=n-2048s, R = (n'>>7)*256 + ((n'>>5)&3)*64 + s*32 + (n'&31)
__global__ void transpose_any(const void* __restrict__ in, u16* __restrict__ out,
                              int K, int N, size_t out_zsz, int rowoff, int mode,
                              const int* __restrict__ flag) {
  bool b16 = flag[0] != 0;
  __shared__ u16 tile[32][33];
  size_t iboff = (size_t)blockIdx.z * K * N;
  size_t oboff = (size_t)blockIdx.z * out_zsz;
  int n0 = blockIdx.x * 32, k0 = blockIdx.y * 32;
  int tx = threadIdx.x, ty = threadIdx.y;
  #pragma unroll
  for (int r = 0; r < 4; r++) {
    float v = ldf(in, iboff + (size_t)(k0 + ty*4 + r) * N + n0 + tx, b16);
    __bf16 bv = (__bf16)v;
    tile[ty*4+r][tx] = __builtin_bit_cast(u16, bv);
  }
  __syncthreads();
  int rbase;
  if (mode == 0) rbase = rowoff + n0;
  else {
    int s = (n0 >= 2048) ? 1 : 0;
    int np = n0 - s*2048;
    rbase = (np >> 7)*256 + ((np >> 5) & 3)*64 + s*32;   // n0 % 32 == 0
  }
  #pragma unroll
  for (int r = 0; r < 4; r++)
    out[oboff + (size_t)(rbase + ty*4 + r) * K + k0 + tx] = tile[tx][ty*4+r];
}

// ---------------- token assembly: x (B,4,512) f32 ----------------
__global__ void build_tokens(const void* __restrict__ text, const void* __restrict__ img,
                             const int* __restrict__ ts, const void* __restrict__ table,
                             const void* __restrict__ lq, float* __restrict__ x,
                             const int* __restrict__ flag) {
  bool b16 = flag[0] != 0;
  int b = blockIdx.x, t = threadIdx.x;
  float* xr = x + (size_t)b * NTOK * DIM;
  int tsb = ts[b];
  for (int e = t; e < DIM; e += 256) {
    xr[e]         = ldf(text,  (size_t)b * DIM + e, b16);
    xr[DIM + e]   = ldf(table, (size_t)tsb * DIM + e, b16);
    xr[2*DIM + e] = ldf(img,   (size_t)b * DIM + e, b16);
    xr[3*DIM + e] = ldf(lq,    (size_t)e, b16);
  }
}

// ---------------- LN: f32 row -> bf16 row ----------------
__global__ void ln_f32_bf16(const float* __restrict__ x, const void* __restrict__ g, size_t goff,
                            __bf16* __restrict__ out, const int* __restrict__ flag) {
  bool b16 = flag[0] != 0;
  __shared__ float sm[8];
  int row = blockIdx.x, t = threadIdx.x;
  float2 v = ((const float2*)(x + (size_t)row * DIM))[t];
  float s = v.x + v.y, s2 = v.x*v.x + v.y*v.y;
  block_reduce2(s, s2, sm);
  float mean = s * (1.f/DIM);
  float var  = s2 * (1.f/DIM) - mean*mean;
  float rs = rsqrtf(var + LN_EPS);
  float g0 = ldf(g, goff + 2*t, b16), g1 = ldf(g, goff + 2*t + 1, b16);
  bf16x2 o2 = { (__bf16)((v.x-mean)*rs*g0), (__bf16)((v.y-mean)*rs*g1) };
  ((bf16x2*)(out + (size_t)row * DIM))[t] = o2;
}

// ---------------- fused: x += LN(y; g1); h = LN(x; g2) ----------------
__global__ void ln_add_ln(const __bf16* __restrict__ y,
                          const void* __restrict__ g1, size_t g1off,
                          const void* __restrict__ g2, size_t g2off,
                          float* __restrict__ x, __bf16* __restrict__ h,
                          const int* __restrict__ flag) {
  bool b16 = flag[0] != 0;
  __shared__ float sm[8];
  int row = blockIdx.x, t = threadIdx.x;
  bf16x2 yv = ((const bf16x2*)(y + (size_t)row * DIM))[t];
  float v0 = (float)yv[0], v1 = (float)yv[1];
  float s = v0 + v1, s2 = v0*v0 + v1*v1;
  block_reduce2(s, s2, sm);
  float mean = s * (1.f/DIM);
  float var  = s2 * (1.f/DIM) - mean*mean;
  float rs = rsqrtf(var + LN_EPS);
  float ga = ldf(g1, g1off + 2*t, b16), gb = ldf(g1, g1off + 2*t + 1, b16);
  float2* xr = (float2*)(x + (size_t)row * DIM);
  float2 xv = xr[t];
  xv.x += (v0-mean)*rs*ga;
  xv.y += (v1-mean)*rs*gb;
  xr[t] = xv;
  float s_  = xv.x + xv.y, s2_ = xv.x*xv.x + xv.y*xv.y;
  block_reduce2(s_, s2_, sm);
  float mean2 = s_ * (1.f/DIM);
  float var2  = s2_ * (1.f/DIM) - mean2*mean2;
  float rs2 = rsqrtf(var2 + LN_EPS);
  float gc = ldf(g2, g2off + 2*t, b16), gd = ldf(g2, g2off + 2*t + 1, b16);
  bf16x2 o2 = { (__bf16)((xv.x-mean2)*rs2*gc), (__bf16)((xv.y-mean2)*rs2*gd) };
  ((bf16x2*)(h + (size_t)row * DIM))[t] = o2;
}

// ---------------- final LN on token 3 rows -> hlast (8192,512) bf16 ----------------
__global__ void ln_final(const float* __restrict__ x, const void* __restrict__ g,
                         __bf16* __restrict__ out, const int* __restrict__ flag) {
  bool b16 = flag[0] != 0;
  __shared__ float sm[8];
  int b = blockIdx.x, t = threadIdx.x;
  int row = b*NTOK + 3;
  float2 v = ((const float2*)(x + (size_t)row * DIM))[t];
  float s = v.x + v.y, s2 = v.x*v.x + v.y*v.y;
  block_reduce2(s, s2, sm);
  float mean = s * (1.f/DIM);
  float var  = s2 * (1.f/DIM) - mean*mean;
  float rs = rsqrtf(var + LN_EPS);
  float g0 = ldf(g, (size_t)2*t, b16), g1 = ldf(g, (size_t)2*t + 1, b16);
  bf16x2 o2 = { (__bf16)((v.x-mean)*rs*g0), (__bf16)((v.y-mean)*rs*g1) };
  ((bf16x2*)(out + (size_t)b * DIM))[t] = o2;
}

// ================= 8-phase pipelined GEMM (256-row tile, counted vmcnt) =================
// BROWS: B-panel rows per block.
// EPI 0: store bf16 (out cols = BROWS)
// EPI 1: swiglu epilogue on interleaved B (out cols = BROWS/2, bf16)
// EPI 2: f32 accumulate (out cols = BROWS)
// EPI 3: store bf16 or f32 per flag (out cols = BROWS)
template<int BROWS, int EPI>
__global__ __launch_bounds__(512, 2) void gemm8(
    const __bf16* __restrict__ A, int lda,
    const __bf16* __restrict__ B, int ldb,
    void* __restrict__ Cv, int ldc, int K, const int* __restrict__ flag)
{
  constexpr int UNITS = (BROWS == 256) ? 4 : 3;   // 128-row staging units per K-tile (A0,A1,B0[,B1])
  constexpr int WCN   = (BROWS == 256) ? 4 : 2;   // waves along N
  constexpr int M_FR  = (BROWS == 256) ? 8 : 4;   // m-frags per wave
  constexpr int QM    = M_FR / 4;                 // m-frags per phase
  __shared__ char ldsmem[2][(256 + BROWS) * 128];

  const int tid = threadIdx.x;
  const int wid = tid >> 6, lane = tid & 63;
  const int wr = wid / WCN, wc = wid % WCN;
  const int lr = lane & 15, lc = lane >> 4;
  const int sr = tid >> 3;                        // staging row within 64-row half-unit
  const int cs = ((tid & 7) ^ (sr & 7)) * 8;      // pre-swizzled source chunk (elems)
  const int bx = blockIdx.x, by = blockIdx.y;

  const __bf16* Ab = A + (size_t)by * 256 * lda;
  const __bf16* Bb = B + (size_t)bx * BROWS * ldb;

  f32x4 acc[M_FR][4] = {};
  const int NT = K >> 6;

  char* lds0 = ldsmem[0];
  char* lds1 = ldsmem[1];

  // stage one 128-row unit (16KB) of tile kt into buffer p. u: 0,1 = A halves; 2,3 = B halves.
  auto stage_unit = [&](int p, int kt, int u) {
    char* base = (p ? lds1 : lds0);
    if (u < 2) {
      const __bf16* s = Ab + (size_t)(u*128 + sr) * lda + kt*64 + cs;
      char* d = base + u*16384 + (wid << 10);
      gld_lds16(s, d);
      gld_lds16(s + (size_t)64 * lda, d + 8192);
    } else {
      const __bf16* s = Bb + (size_t)((u-2)*128 + sr) * ldb + kt*64 + cs;
      char* d = base + 32768 + (u-2)*16384 + (wid << 10);
      gld_lds16(s, d);
      gld_lds16(s + (size_t)64 * ldb, d + 8192);
    }
  };

  // prologue: tile 0 -> buf0
  #pragma unroll
  for (int u = 0; u < UNITS; u++) stage_unit(0, 0, u);

  const int NIT = NT >> 1;
  for (int i = 0; i < NIT; i++) {
    const int t1 = 2*i + 1;
    const int t2 = (2*i + 2 < NT) ? (2*i + 2) : 0;   // clamped (keeps vmcnt counts uniform)
    #pragma unroll
    for (int hfl = 0; hfl < 2; hfl++) {
      char* cbase = hfl ? lds1 : lds0;               // compute buffer
      const int sp = hfl ^ 1;                        // staging buffer
      const int st = hfl ? t2 : t1;                  // staging tile
      bf16x8 bfr[4][2];
      #pragma unroll
      for (int q = 0; q < 4; q++) {
        if (q < UNITS) stage_unit(sp, st, q);
        if (q == 0) {
          asm volatile("s_waitcnt vmcnt(2)" ::: "memory");
          asm volatile("s_barrier" ::: "memory");
          #pragma unroll
          for (int f = 0; f < 4; f++)
            #pragma unroll
            for (int kk = 0; kk < 2; kk++) {
              int row = wc*64 + f*16 + lr;
              int ch = (kk*4 + lc) ^ (lr & 7);
              bfr[f][kk] = *(const bf16x8*)(cbase + 32768 + row*128 + ch*16);
            }
        }
        bf16x8 afr[QM][2];
        #pragma unroll
        for (int m2 = 0; m2 < QM; m2++)
          #pragma unroll
          for (int kk = 0; kk < 2; kk++) {
            int row = wr*(M_FR*16) + (q*QM + m2)*16 + lr;
            int ch = (kk*4 + lc) ^ (lr & 7);
            afr[m2][kk] = *(const bf16x8*)(cbase + row*128 + ch*16);
          }
        __builtin_amdgcn_s_setprio(1);
        #pragma unroll
        for (int m2 = 0; m2 < QM; m2++)
          #pragma unroll
          for (int n = 0; n < 4; n++)
            #pragma unroll
            for (int kk = 0; kk < 2; kk++)
              acc[q*QM + m2][n] = __builtin_amdgcn_mfma_f32_16x16x32_bf16(
                  afr[m2][kk], bfr[n][kk], acc[q*QM + m2][n], 0, 0, 0);
        __builtin_amdgcn_s_setprio(0);
        asm volatile("s_barrier" ::: "memory");
      }
    }
  }

  if (EPI == 1) {
    // swiglu on interleaved B: frag f in {0,1} = a, f+2 = g, same output col.
    __bf16* Ob = (__bf16*)Cv;
    const int colb = bx*128 + wc*32 + lr;
    const int rowb = by*256 + wr*128 + lc*4;
    #pragma unroll
    for (int m = 0; m < M_FR; m++)
      #pragma unroll
      for (int rr = 0; rr < 4; rr++) {
        size_t ro = (size_t)(rowb + m*16 + rr) * ldc;
        #pragma unroll
        for (int fa = 0; fa < 2; fa++) {
          float a = acc[m][fa][rr], g = acc[m][fa+2][rr];
          Ob[ro + colb + fa*16] = (__bf16)(a * g / (1.f + __expf(-g)));
        }
      }
  } else if (EPI == 2) {
    float* Xf = (float*)Cv;
    const int colb = bx*BROWS + wc*64 + lr;
    const int rowb = by*256 + wr*(M_FR*16) + lc*4;
    #pragma unroll
    for (int m = 0; m < M_FR; m++)
      #pragma unroll
      for (int rr = 0; rr < 4; rr++) {
        size_t ro = (size_t)(rowb + m*16 + rr) * ldc;
        #pragma unroll
        for (int n = 0; n < 4; n++) Xf[ro + colb + n*16] += acc[m][n][rr];
      }
  } else if (EPI == 0) {
    __bf16* Cb = (__bf16*)Cv;
    const int colb = bx*BROWS + wc*64 + lr;
    const int rowb = by*256 + wr*(M_FR*16) + lc*4;
    #pragma unroll
    for (int m = 0; m < M_FR; m++)
      #pragma unroll
      for (int rr = 0; rr < 4; rr++) {
        size_t ro = (size_t)(rowb + m*16 + rr) * ldc;
        #pragma unroll
        for (int n = 0; n < 4; n++) Cb[ro + colb + n*16] = (__bf16)acc[m][n][rr];
      }
  } else {
    bool b16o = flag[0] != 0;
    __bf16* Cb = (__bf16*)Cv;
    float*  Cf = (float*)Cv;
    const int colb = bx*BROWS + wc*64 + lr;
    const int rowb = by*256 + wr*(M_FR*16) + lc*4;
    #pragma unroll
    for (int m = 0; m < M_FR; m++)
      #pragma unroll
      for (int rr = 0; rr < 4; rr++) {
        size_t ro = (size_t)(rowb + m*16 + rr) * ldc;
        #pragma unroll
        for (int n = 0; n < 4; n++) {
          float val = acc[m][n][rr];
          if (b16o) Cb[ro + colb + n*16] = (__bf16)val; else Cf[ro + colb + n*16] = val;
        }
      }
  }
}

// ---------------- fused attention, 16-lane-group layout ----------------
// Each 16-lane group serves one (b,h); lane c holds d = 4c..4c+3 (f32).
// Wave = 4 (b,h) of the SAME b (k/v shared, SIMD-redundant at no cost).
// Block = 256 threads = 16 bh = 2 batches. Grid = BATCH/2.
__global__ __launch_bounds__(256) void attn_kernel(
    const __bf16* __restrict__ qkv,
    const void* __restrict__ nkv_all, int layer, const void* __restrict__ rel_emb,
    __bf16* __restrict__ ao, const int* __restrict__ flag)
{
  bool b16 = flag[0] != 0;
  const int tid = threadIdx.x;
  const int w = tid >> 6, l = tid & 63;
  const int g = l >> 4, c = l & 15;
  const int bh = blockIdx.x * 16 + w * 4 + g;
  const int b = bh >> 3, h = bh & 7;
  const bool rot = (c < 8);   // d = 4c..4c+3 < 32

  const float LN1E4_32 = 9.210340371976184f * (1.f/32.f);
  float inv0 = __expf(-(float)(4*c)     * LN1E4_32);
  float inv1 = __expf(-(float)(4*c + 2) * LN1E4_32);
  float cs0[4], sn0[4], cs1[4], sn1[4];
  #pragma unroll
  for (int t = 0; t < 4; t++) {
    __sincosf((float)t * inv0, &sn0[t], &cs0[t]);
    __sincosf((float)t * inv1, &sn1[t], &cs1[t]);
  }
  float rb[4];
  #pragma unroll
  for (int t = 0; t < 4; t++) rb[t] = ldf(rel_emb, (size_t)t * 8 + h, b16);

  float q[4][4];
  #pragma unroll
  for (int i = 0; i < 4; i++) {
    bf16x4 qv = *(const bf16x4*)(qkv + ((size_t)(b*NTOK + i)) * 640 + h*DH + c*4);
    float v0 = (float)qv[0], v1 = (float)qv[1], v2 = (float)qv[2], v3 = (float)qv[3];
    if (rot) {
      float n0 = v0*cs0[i] - v1*sn0[i], n1 = v1*cs0[i] + v0*sn0[i];
      float n2 = v2*cs1[i] - v3*sn1[i], n3 = v3*cs1[i] + v2*sn1[i];
      v0 = n0; v1 = n1; v2 = n2; v3 = n3;
    }
    q[i][0] = v0; q[i][1] = v1; q[i][2] = v2; q[i][3] = v3;
  }
  #pragma unroll
  for (int i = 0; i < 4; i++) {
    float ss = q[i][0]*q[i][0] + q[i][1]*q[i][1] + q[i][2]*q[i][2] + q[i][3]*q[i][3];
    float r = 1.f / fmaxf(sqrtf(gsum16(ss)), 1e-12f);
    #pragma unroll
    for (int e = 0; e < 4; e++) q[i][e] *= r;
  }

  float kk[5][4], vv[5][4];
  #pragma unroll
  for (int e = 0; e < 4; e++) {
    kk[0][e] = ldf(nkv_all, (size_t)layer*128 + c*4 + e, b16);
    vv[0][e] = ldf(nkv_all, (size_t)layer*128 + 64 + c*4 + e, b16);
  }
  #pragma unroll
  for (int j = 1; j < 5; j++) {
    const __bf16* base = qkv + ((size_t)(b*NTOK + j - 1)) * 640 + 512;
    bf16x4 kv4 = *(const bf16x4*)(base + c*4);
    bf16x4 vv4 = *(const bf16x4*)(base + 64 + c*4);
    float v0 = (float)kv4[0], v1 = (float)kv4[1], v2 = (float)kv4[2], v3 = (float)kv4[3];
    if (rot) {
      int t = j - 1;
      float n0 = v0*cs0[t] - v1*sn0[t], n1 = v1*cs0[t] + v0*sn0[t];
      float n2 = v2*cs1[t] - v3*sn1[t], n3 = v3*cs1[t] + v2*sn1[t];
      v0 = n0; v1 = n1; v2 = n2; v3 = n3;
    }
    kk[j][0] = v0; kk[j][1] = v1; kk[j][2] = v2; kk[j][3] = v3;
    #pragma unroll
    for (int e = 0; e < 4; e++) vv[j][e] = (float)vv4[e];
  }
  #pragma unroll
  for (int j = 0; j < 5; j++) {
    float ss = kk[j][0]*kk[j][0] + kk[j][1]*kk[j][1] + kk[j][2]*kk[j][2] + kk[j][3]*kk[j][3];
    float r = 1.f / fmaxf(sqrtf(gsum16(ss)), 1e-12f);
    #pragma unroll
    for (int e = 0; e < 4; e++) kk[j][e] *= r;
  }

  #pragma unroll
  for (int i = 0; i < 4; i++) {
    float sim[5];
    #pragma unroll
    for (int j = 0; j < 5; j++) {
      if (j > i + 1) break;
      float pp = q[i][0]*kk[j][0] + q[i][1]*kk[j][1] + q[i][2]*kk[j][2] + q[i][3]*kk[j][3];
      sim[j] = 16.f * gsum16(pp) + rb[(i - j > 0) ? (i - j) : 0];
    }
    float m = sim[0];
    #pragma unroll
    for (int j = 1; j < 5; j++) { if (j > i + 1) break; m = fmaxf(m, sim[j]); }
    float Z = 0.f, o0 = 0.f, o1 = 0.f, o2 = 0.f, o3 = 0.f;
    #pragma unroll
    for (int j = 0; j < 5; j++) {
      if (j > i + 1) break;
      float e = __expf(sim[j] - m);
      Z += e;
      o0 += e * vv[j][0]; o1 += e * vv[j][1]; o2 += e * vv[j][2]; o3 += e * vv[j][3];
    }
    float rz = 1.f / Z;
    bf16x4 ov = { (__bf16)(o0*rz), (__bf16)(o1*rz), (__bf16)(o2*rz), (__bf16)(o3*rz) };
    *(bf16x4*)(ao + ((size_t)(b*NTOK + i)) * DIM + h*DH + c*4) = ov;
  }
}

// ---------------- launch ----------------
extern "C" void kernel_launch(void* const* d_in, const int* in_sizes, int n_in,
                              void* d_out, int out_size, void* d_ws, size_t ws_size,
                              hipStream_t stream) {
  const void* image_embed     = d_in[0];
  const void* text_embed      = d_in[1];
  const int*  timesteps       = (const int*)d_in[2];
  const void* time_table      = d_in[3];
  const void* learned_query   = d_in[4];
  const void* rel_emb         = d_in[5];
  const void* attn_norm_g     = d_in[6];
  const void* Wq              = d_in[7];
  const void* Wkv             = d_in[8];
  const void* null_kv         = d_in[9];
  const void* Wo              = d_in[10];
  const void* attn_out_norm_g = d_in[11];
  const void* ff_norm_g       = d_in[12];
  const void* Wff1            = d_in[13];
  const void* Wff2            = d_in[14];
  const void* final_norm_g    = d_in[15];
  const void* Wproj           = d_in[16];

  if (ws_size < WS_NEED) return;

  char* ws = (char*)d_ws;
  __bf16* wqkv = (__bf16*)(ws + OFF_WQKV);
  __bf16* wto  = (__bf16*)(ws + OFF_WTO);
  __bf16* wtf1 = (__bf16*)(ws + OFF_WTF1);   // interleaved
  __bf16* wtf2 = (__bf16*)(ws + OFF_WTF2);
  __bf16* wtp  = (__bf16*)(ws + OFF_WTP);
  float*  x    = (float*) (ws + OFF_X);
  __bf16* h    = (__bf16*)(ws + OFF_H);
  __bf16* qkv  = (__bf16*)(ws + OFF_QKV);   // also y; FF act buffer starts here
  __bf16* ao   = (__bf16*)(ws + OFF_AO);    // attn_out / hlast
  __bf16* act  = (__bf16*)(ws + OFF_QKV);   // 16384 x 2048 bf16 (67MB)
  int*    flag = (int*)   (ws + OFF_FLAG);

  detect_dtype<<<1, 256, 0, stream>>>((const unsigned int*)Wq, flag);

  dim3 tb(32, 8);
  transpose_any<<<dim3(16, 16, 12),  tb, 0, stream>>>(Wq,   (u16*)wqkv, 512,  512,  640ull*512, 0,   0, flag);
  transpose_any<<<dim3(4,  16, 12),  tb, 0, stream>>>(Wkv,  (u16*)wqkv, 512,  128,  640ull*512, 512, 0, flag);
  transpose_any<<<dim3(16, 16, 12),  tb, 0, stream>>>(Wo,   (u16*)wto,  512,  512,  512ull*512, 0,   0, flag);
  transpose_any<<<dim3(128,16, 12),  tb, 0, stream>>>(Wff1, (u16*)wtf1, 512,  4096, 4096ull*512,0,   1, flag);
  transpose_any<<<dim3(16, 64, 12),  tb, 0, stream>>>(Wff2, (u16*)wtf2, 2048, 512,  512ull*2048,0,   0, flag);
  transpose_any<<<dim3(16, 16, 1),   tb, 0, stream>>>(Wproj,(u16*)wtp,  512,  512,  512ull*512, 0,   0, flag);

  build_tokens<<<BATCH, 256, 0, stream>>>(text_embed, image_embed, timesteps, time_table,
                                          learned_query, x, flag);

  for (int l = 0; l < DEPTH; l++) {
    const __bf16* wqkv_l = wqkv + (size_t)l * 640 * 512;
    const __bf16* wto_l  = wto  + (size_t)l * 512 * 512;
    const __bf16* wtf1_l = wtf1 + (size_t)l * 4096 * 512;
    const __bf16* wtf2_l = wtf2 + (size_t)l * 512 * 2048;

    // attention block
    ln_f32_bf16<<<ROWS, 256, 0, stream>>>(x, attn_norm_g, (size_t)l*DIM, h, flag);
    gemm8<128,0><<<dim3(5, 128), 512, 0, stream>>>(h, DIM, wqkv_l, 512, qkv, 640, 512, flag);
    attn_kernel<<<BATCH/2, 256, 0, stream>>>(qkv, null_kv, l, rel_emb, ao, flag);
    gemm8<128,0><<<dim3(4, 128), 512, 0, stream>>>(ao, DIM, wto_l, 512, qkv /*y*/, DIM, 512, flag);
    ln_add_ln<<<ROWS, 256, 0, stream>>>(qkv /*y*/, attn_out_norm_g, (size_t)l*DIM,
                                        ff_norm_g, (size_t)l*DIM, x, h, flag);

    // FF: two M-chunks of 16384 rows; act = 16384 x 2048 bf16
    for (int c = 0; c < 2; c++) {
      const __bf16* hc = h + (size_t)c * 16384 * DIM;
      float*        xc = x + (size_t)c * 16384 * DIM;
      gemm8<256,1><<<dim3(16, 64), 512, 0, stream>>>(hc, DIM, wtf1_l, 512, act, FFI, 512, flag);
      gemm8<128,2><<<dim3(4, 64), 512, 0, stream>>>(act, FFI, wtf2_l, FFI, xc, DIM, 2048, flag);
    }
  }

  ln_final<<<BATCH, 256, 0, stream>>>(x, final_norm_g, ao /*hlast*/, flag);
  gemm8<128,3><<<dim3(4, 32), 512, 0, stream>>>(ao, DIM, wtp, 512, d_out, DIM, 512, flag);
}

// Round 14
// 5142.142 us; speedup vs baseline: 1.1110x; 1.0466x over previous
//
#include <hip/hip_runtime.h>

typedef __bf16 bf16x8 __attribute__((ext_vector_type(8)));
typedef __bf16 bf16x4 __attribute__((ext_vector_type(4)));
typedef __bf16 bf16x2 __attribute__((ext_vector_type(2)));
typedef float  f32x4  __attribute__((ext_vector_type(4)));
typedef unsigned short u16;

// ---------------- constants ----------------
#define BATCH   8192
#define NTOK    4
#define ROWS    (BATCH*NTOK)      // 32768
#define DIM     512
#define HEADS   8
#define DH      64
#define FFI     2048              // FF_INNER
#define DEPTH   12
#define LN_EPS  1e-5f

// ---------------- workspace layout (bytes) ----------------
static const size_t OFF_WQKV = 0;                               // (12, 640, 512) bf16
static const size_t SZ_WQKV  = 12ull*640*512*2;
static const size_t OFF_WTO  = OFF_WQKV + SZ_WQKV;
static const size_t SZ_WTO   = 12ull*512*512*2;
static const size_t OFF_WTF1 = OFF_WTO + SZ_WTO;                // interleaved layout (12,4096,512)
static const size_t SZ_WTF1  = 12ull*4096*512*2;
static const size_t OFF_WTF2 = OFF_WTF1 + SZ_WTF1;
static const size_t SZ_WTF2  = 12ull*512*2048*2;
static const size_t OFF_WTP  = OFF_WTF2 + SZ_WTF2;
static const size_t SZ_WTP   = 512ull*512*2;
static const size_t OFF_X    = OFF_WTP + SZ_WTP;                // f32 (32768,512)
static const size_t OFF_H    = OFF_X    + (size_t)ROWS*DIM*4;   // h full; layer-11: x3 f32 (16.8MB)
static const size_t OFF_QKV  = OFF_H    + (size_t)ROWS*DIM*2;   // (32768,640) bf16; also y; act
static const size_t OFF_AO   = OFF_QKV  + (size_t)ROWS*640*2;   // attn_out; layer-11: 4x 8.4MB slots
static const size_t OFF_FLAG = OFF_AO   + (size_t)ROWS*DIM*2;
static const size_t WS_NEED  = OFF_FLAG + 256;                  // ~266 MB
// Layer-11 compact buffers (8192x512): h3/h3b @AO+0, q3/hlast @AO+8.4M, ao3 @AO+16.8M,
// y3 @AO+25.2M. x3 (f32 16.8MB) aliases h region (dead after q3/kv GEMMs).
// act3 (8192x2048 bf16 = 33.5MB) aliases qkv region (kv dead after attn3).

// ---------------- helpers ----------------
__device__ __forceinline__ float ldf(const void* p, size_t i, bool b16) {
  return b16 ? (float)((const __bf16*)p)[i] : ((const float*)p)[i];
}

__device__ __forceinline__ void gld_lds16(const void* g, void* l) {
  __builtin_amdgcn_global_load_lds((const __attribute__((address_space(1))) void*)g,
                                   (__attribute__((address_space(3))) void*)l, 16, 0, 0);
}

// 16-lane-group sum (xor butterfly, offsets 8..1 stay within the group)
__device__ __forceinline__ float gsum16(float v) {
  #pragma unroll
  for (int o = 8; o > 0; o >>= 1) v += __shfl_xor(v, o, 64);
  return v;
}

// 256-thread block reduce of (a,b); barrier-balanced so it is safe to call twice
__device__ __forceinline__ void block_reduce2(float& a, float& b, float* sm) {
  #pragma unroll
  for (int o = 32; o > 0; o >>= 1) { a += __shfl_down(a, o, 64); b += __shfl_down(b, o, 64); }
  int lane = threadIdx.x & 63, w = threadIdx.x >> 6;
  __syncthreads();
  if (lane == 0) { sm[w] = a; sm[4+w] = b; }
  __syncthreads();
  a = sm[0]+sm[1]+sm[2]+sm[3];
  b = sm[4]+sm[5]+sm[6]+sm[7];
}

// ---------------- dtype detection: 1 block, writes flag (1 = bf16, 0 = fp32) ----------------
__global__ void detect_dtype(const unsigned int* __restrict__ w, int* __restrict__ flag) {
  __shared__ int cnt[4];
  int t = threadIdx.x;
  int c = 0;
  for (int i = t; i < 2048; i += 256) {
    unsigned int v = w[i];
    unsigned int lo = v & 0xFFFFu, hi = v >> 16;
    int elo = (int)((lo >> 7) & 0xFF), ehi = (int)((hi >> 7) & 0xFF);
    bool okl = (lo == 0u) || (elo >= 100 && elo <= 140);
    bool okh = (hi == 0u) || (ehi >= 100 && ehi <= 140);
    if (okl && okh) c++;
  }
  #pragma unroll
  for (int o = 32; o > 0; o >>= 1) c += __shfl_down(c, o, 64);
  if ((t & 63) == 0) cnt[t >> 6] = c;
  __syncthreads();
  if (t == 0) flag[0] = (cnt[0] + cnt[1] + cnt[2] + cnt[3] > 1024) ? 1 : 0;
}

// ---------------- weight transpose (K,N)->(N,K), optional ff1 interleave ----------------
__global__ void transpose_any(const void* __restrict__ in, u16* __restrict__ out,
                              int K, int N, size_t out_zsz, int rowoff, int mode,
                              const int* __restrict__ flag) {
  bool b16 = flag[0] != 0;
  __shared__ u16 tile[32][33];
  size_t iboff = (size_t)blockIdx.z * K * N;
  size_t oboff = (size_t)blockIdx.z * out_zsz;
  int n0 = blockIdx.x * 32, k0 = blockIdx.y * 32;
  int tx = threadIdx.x, ty = threadIdx.y;
  #pragma unroll
  for (int r = 0; r < 4; r++) {
    float v = ldf(in, iboff + (size_t)(k0 + ty*4 + r) * N + n0 + tx, b16);
    __bf16 bv = (__bf16)v;
    tile[ty*4+r][tx] = __builtin_bit_cast(u16, bv);
  }
  __syncthreads();
  int rbase;
  if (mode == 0) rbase = rowoff + n0;
  else {
    int s = (n0 >= 2048) ? 1 : 0;
    int np = n0 - s*2048;
    rbase = (np >> 7)*256 + ((np >> 5) & 3)*64 + s*32;   // n0 % 32 == 0
  }
  #pragma unroll
  for (int r = 0; r < 4; r++)
    out[oboff + (size_t)(rbase + ty*4 + r) * K + k0 + tx] = tile[tx][ty*4+r];
}

// ---------------- token assembly: x (B,4,512) f32 ----------------
__global__ void build_tokens(const void* __restrict__ text, const void* __restrict__ img,
                             const int* __restrict__ ts, const void* __restrict__ table,
                             const void* __restrict__ lq, float* __restrict__ x,
                             const int* __restrict__ flag) {
  bool b16 = flag[0] != 0;
  int b = blockIdx.x, t = threadIdx.x;
  float* xr = x + (size_t)b * NTOK * DIM;
  int tsb = ts[b];
  for (int e = t; e < DIM; e += 256) {
    xr[e]         = ldf(text,  (size_t)b * DIM + e, b16);
    xr[DIM + e]   = ldf(table, (size_t)tsb * DIM + e, b16);
    xr[2*DIM + e] = ldf(img,   (size_t)b * DIM + e, b16);
    xr[3*DIM + e] = ldf(lq,    (size_t)e, b16);
  }
}

// ---------------- LN: f32 row -> bf16 row ----------------
__global__ void ln_f32_bf16(const float* __restrict__ x, const void* __restrict__ g, size_t goff,
                            __bf16* __restrict__ out, const int* __restrict__ flag) {
  bool b16 = flag[0] != 0;
  __shared__ float sm[8];
  int row = blockIdx.x, t = threadIdx.x;
  float2 v = ((const float2*)(x + (size_t)row * DIM))[t];
  float s = v.x + v.y, s2 = v.x*v.x + v.y*v.y;
  block_reduce2(s, s2, sm);
  float mean = s * (1.f/DIM);
  float var  = s2 * (1.f/DIM) - mean*mean;
  float rs = rsqrtf(var + LN_EPS);
  float g0 = ldf(g, goff + 2*t, b16), g1 = ldf(g, goff + 2*t + 1, b16);
  bf16x2 o2 = { (__bf16)((v.x-mean)*rs*g0), (__bf16)((v.y-mean)*rs*g1) };
  ((bf16x2*)(out + (size_t)row * DIM))[t] = o2;
}

// ---------------- fused: x += LN(y; g1); h = LN(x; g2) ----------------
__global__ void ln_add_ln(const __bf16* __restrict__ y,
                          const void* __restrict__ g1, size_t g1off,
                          const void* __restrict__ g2, size_t g2off,
                          float* __restrict__ x, __bf16* __restrict__ h,
                          const int* __restrict__ flag) {
  bool b16 = flag[0] != 0;
  __shared__ float sm[8];
  int row = blockIdx.x, t = threadIdx.x;
  bf16x2 yv = ((const bf16x2*)(y + (size_t)row * DIM))[t];
  float v0 = (float)yv[0], v1 = (float)yv[1];
  float s = v0 + v1, s2 = v0*v0 + v1*v1;
  block_reduce2(s, s2, sm);
  float mean = s * (1.f/DIM);
  float var  = s2 * (1.f/DIM) - mean*mean;
  float rs = rsqrtf(var + LN_EPS);
  float ga = ldf(g1, g1off + 2*t, b16), gb = ldf(g1, g1off + 2*t + 1, b16);
  float2* xr = (float2*)(x + (size_t)row * DIM);
  float2 xv = xr[t];
  xv.x += (v0-mean)*rs*ga;
  xv.y += (v1-mean)*rs*gb;
  xr[t] = xv;
  float s_  = xv.x + xv.y, s2_ = xv.x*xv.x + xv.y*xv.y;
  block_reduce2(s_, s2_, sm);
  float mean2 = s_ * (1.f/DIM);
  float var2  = s2_ * (1.f/DIM) - mean2*mean2;
  float rs2 = rsqrtf(var2 + LN_EPS);
  float gc = ldf(g2, g2off + 2*t, b16), gd = ldf(g2, g2off + 2*t + 1, b16);
  bf16x2 o2 = { (__bf16)((xv.x-mean2)*rs2*gc), (__bf16)((xv.y-mean2)*rs2*gd) };
  ((bf16x2*)(h + (size_t)row * DIM))[t] = o2;
}

// ---------------- layer-11 compact: x3[r] = x[r*4+3] + LN(y3[r]); h3b[r] = LN(x3[r]) ------
__global__ void ln_add3(const __bf16* __restrict__ y3,
                        const void* __restrict__ g1, size_t g1off,
                        const void* __restrict__ g2, size_t g2off,
                        const float* __restrict__ xfull, float* __restrict__ x3,
                        __bf16* __restrict__ h3b, const int* __restrict__ flag) {
  bool b16 = flag[0] != 0;
  __shared__ float sm[8];
  int r = blockIdx.x, t = threadIdx.x;
  bf16x2 yv = ((const bf16x2*)(y3 + (size_t)r * DIM))[t];
  float v0 = (float)yv[0], v1 = (float)yv[1];
  float s = v0 + v1, s2 = v0*v0 + v1*v1;
  block_reduce2(s, s2, sm);
  float mean = s * (1.f/DIM);
  float var  = s2 * (1.f/DIM) - mean*mean;
  float rs = rsqrtf(var + LN_EPS);
  float ga = ldf(g1, g1off + 2*t, b16), gb = ldf(g1, g1off + 2*t + 1, b16);
  float2 xv = ((const float2*)(xfull + (size_t)(r*NTOK + 3) * DIM))[t];
  xv.x += (v0-mean)*rs*ga;
  xv.y += (v1-mean)*rs*gb;
  ((float2*)(x3 + (size_t)r * DIM))[t] = xv;
  float s_  = xv.x + xv.y, s2_ = xv.x*xv.x + xv.y*xv.y;
  block_reduce2(s_, s2_, sm);
  float mean2 = s_ * (1.f/DIM);
  float var2  = s2_ * (1.f/DIM) - mean2*mean2;
  float rs2 = rsqrtf(var2 + LN_EPS);
  float gc = ldf(g2, g2off + 2*t, b16), gd = ldf(g2, g2off + 2*t + 1, b16);
  bf16x2 o2 = { (__bf16)((xv.x-mean2)*rs2*gc), (__bf16)((xv.y-mean2)*rs2*gd) };
  ((bf16x2*)(h3b + (size_t)r * DIM))[t] = o2;
}

// ---------------- final LN on compact x3 rows -> hlast (8192,512) bf16 ----------------
__global__ void ln_final3(const float* __restrict__ x3, const void* __restrict__ g,
                          __bf16* __restrict__ out, const int* __restrict__ flag) {
  bool b16 = flag[0] != 0;
  __shared__ float sm[8];
  int b = blockIdx.x, t = threadIdx.x;
  float2 v = ((const float2*)(x3 + (size_t)b * DIM))[t];
  float s = v.x + v.y, s2 = v.x*v.x + v.y*v.y;
  block_reduce2(s, s2, sm);
  float mean = s * (1.f/DIM);
  float var  = s2 * (1.f/DIM) - mean*mean;
  float rs = rsqrtf(var + LN_EPS);
  float g0 = ldf(g, (size_t)2*t, b16), g1 = ldf(g, (size_t)2*t + 1, b16);
  bf16x2 o2 = { (__bf16)((v.x-mean)*rs*g0), (__bf16)((v.y-mean)*rs*g1) };
  ((bf16x2*)(out + (size_t)b * DIM))[t] = o2;
}

// ---------------- gather token-3 rows: h3[r] = h[r*4+3] ----------------
__global__ void gather3(const __bf16* __restrict__ h, __bf16* __restrict__ h3) {
  int lane = threadIdx.x & 63;
  int r = blockIdx.x * 4 + (threadIdx.x >> 6);
  *(bf16x8*)(h3 + (size_t)r * DIM + lane*8) =
      *(const bf16x8*)(h + (size_t)(r*NTOK + 3) * DIM + lane*8);
}

// ================= 8-phase pipelined GEMM (256-row tile, counted vmcnt) =================
// EXACT r6 schedule — proven optimum; do not perturb.
// EPI 0: bf16; EPI 1: swiglu (interleaved B, out cols=BROWS/2); EPI 2: f32 +=; EPI 3: per-flag.
template<int BROWS, int EPI>
__global__ __launch_bounds__(512, 2) void gemm8(
    const __bf16* __restrict__ A, int lda,
    const __bf16* __restrict__ B, int ldb,
    void* __restrict__ Cv, int ldc, int K, const int* __restrict__ flag)
{
  constexpr int UNITS = (BROWS == 256) ? 4 : 3;
  constexpr int WCN   = (BROWS == 256) ? 4 : 2;
  constexpr int M_FR  = (BROWS == 256) ? 8 : 4;
  constexpr int QM    = M_FR / 4;
  __shared__ char ldsmem[2][(256 + BROWS) * 128];

  const int tid = threadIdx.x;
  const int wid = tid >> 6, lane = tid & 63;
  const int wr = wid / WCN, wc = wid % WCN;
  const int lr = lane & 15, lc = lane >> 4;
  const int sr = tid >> 3;
  const int cs = ((tid & 7) ^ (sr & 7)) * 8;
  const int bx = blockIdx.x, by = blockIdx.y;

  const __bf16* Ab = A + (size_t)by * 256 * lda;
  const __bf16* Bb = B + (size_t)bx * BROWS * ldb;

  f32x4 acc[M_FR][4] = {};
  const int NT = K >> 6;

  char* lds0 = ldsmem[0];
  char* lds1 = ldsmem[1];

  auto stage_unit = [&](int p, int kt, int u) {
    char* base = (p ? lds1 : lds0);
    if (u < 2) {
      const __bf16* s = Ab + (size_t)(u*128 + sr) * lda + kt*64 + cs;
      char* d = base + u*16384 + (wid << 10);
      gld_lds16(s, d);
      gld_lds16(s + (size_t)64 * lda, d + 8192);
    } else {
      const __bf16* s = Bb + (size_t)((u-2)*128 + sr) * ldb + kt*64 + cs;
      char* d = base + 32768 + (u-2)*16384 + (wid << 10);
      gld_lds16(s, d);
      gld_lds16(s + (size_t)64 * ldb, d + 8192);
    }
  };

  #pragma unroll
  for (int u = 0; u < UNITS; u++) stage_unit(0, 0, u);

  const int NIT = NT >> 1;
  for (int i = 0; i < NIT; i++) {
    const int t1 = 2*i + 1;
    const int t2 = (2*i + 2 < NT) ? (2*i + 2) : 0;
    #pragma unroll
    for (int hfl = 0; hfl < 2; hfl++) {
      char* cbase = hfl ? lds1 : lds0;
      const int sp = hfl ^ 1;
      const int st = hfl ? t2 : t1;
      bf16x8 bfr[4][2];
      #pragma unroll
      for (int q = 0; q < 4; q++) {
        if (q < UNITS) stage_unit(sp, st, q);
        if (q == 0) {
          asm volatile("s_waitcnt vmcnt(2)" ::: "memory");
          asm volatile("s_barrier" ::: "memory");
          #pragma unroll
          for (int f = 0; f < 4; f++)
            #pragma unroll
            for (int kk = 0; kk < 2; kk++) {
              int row = wc*64 + f*16 + lr;
              int ch = (kk*4 + lc) ^ (lr & 7);
              bfr[f][kk] = *(const bf16x8*)(cbase + 32768 + row*128 + ch*16);
            }
        }
        bf16x8 afr[QM][2];
        #pragma unroll
        for (int m2 = 0; m2 < QM; m2++)
          #pragma unroll
          for (int kk = 0; kk < 2; kk++) {
            int row = wr*(M_FR*16) + (q*QM + m2)*16 + lr;
            int ch = (kk*4 + lc) ^ (lr & 7);
            afr[m2][kk] = *(const bf16x8*)(cbase + row*128 + ch*16);
          }
        __builtin_amdgcn_s_setprio(1);
        #pragma unroll
        for (int m2 = 0; m2 < QM; m2++)
          #pragma unroll
          for (int n = 0; n < 4; n++)
            #pragma unroll
            for (int kk = 0; kk < 2; kk++)
              acc[q*QM + m2][n] = __builtin_amdgcn_mfma_f32_16x16x32_bf16(
                  afr[m2][kk], bfr[n][kk], acc[q*QM + m2][n], 0, 0, 0);
        __builtin_amdgcn_s_setprio(0);
        asm volatile("s_barrier" ::: "memory");
      }
    }
  }

  if (EPI == 1) {
    __bf16* Ob = (__bf16*)Cv;
    const int colb = bx*128 + wc*32 + lr;
    const int rowb = by*256 + wr*128 + lc*4;
    #pragma unroll
    for (int m = 0; m < M_FR; m++)
      #pragma unroll
      for (int rr = 0; rr < 4; rr++) {
        size_t ro = (size_t)(rowb + m*16 + rr) * ldc;
        #pragma unroll
        for (int fa = 0; fa < 2; fa++) {
          float a = acc[m][fa][rr], g = acc[m][fa+2][rr];
          Ob[ro + colb + fa*16] = (__bf16)(a * g / (1.f + __expf(-g)));
        }
      }
  } else if (EPI == 2) {
    float* Xf = (float*)Cv;
    const int colb = bx*BROWS + wc*64 + lr;
    const int rowb = by*256 + wr*(M_FR*16) + lc*4;
    #pragma unroll
    for (int m = 0; m < M_FR; m++)
      #pragma unroll
      for (int rr = 0; rr < 4; rr++) {
        size_t ro = (size_t)(rowb + m*16 + rr) * ldc;
        #pragma unroll
        for (int n = 0; n < 4; n++) Xf[ro + colb + n*16] += acc[m][n][rr];
      }
  } else if (EPI == 0) {
    __bf16* Cb = (__bf16*)Cv;
    const int colb = bx*BROWS + wc*64 + lr;
    const int rowb = by*256 + wr*(M_FR*16) + lc*4;
    #pragma unroll
    for (int m = 0; m < M_FR; m++)
      #pragma unroll
      for (int rr = 0; rr < 4; rr++) {
        size_t ro = (size_t)(rowb + m*16 + rr) * ldc;
        #pragma unroll
        for (int n = 0; n < 4; n++) Cb[ro + colb + n*16] = (__bf16)acc[m][n][rr];
      }
  } else {
    bool b16o = flag[0] != 0;
    __bf16* Cb = (__bf16*)Cv;
    float*  Cf = (float*)Cv;
    const int colb = bx*BROWS + wc*64 + lr;
    const int rowb = by*256 + wr*(M_FR*16) + lc*4;
    #pragma unroll
    for (int m = 0; m < M_FR; m++)
      #pragma unroll
      for (int rr = 0; rr < 4; rr++) {
        size_t ro = (size_t)(rowb + m*16 + rr) * ldc;
        #pragma unroll
        for (int n = 0; n < 4; n++) {
          float val = acc[m][n][rr];
          if (b16o) Cb[ro + colb + n*16] = (__bf16)val; else Cf[ro + colb + n*16] = val;
        }
      }
  }
}

// ---------------- fused attention, 16-lane-group layout (layers 0..10) ----------------
__global__ __launch_bounds__(256) void attn_kernel(
    const __bf16* __restrict__ qkv,
    const void* __restrict__ nkv_all, int layer, const void* __restrict__ rel_emb,
    __bf16* __restrict__ ao, const int* __restrict__ flag)
{
  bool b16 = flag[0] != 0;
  const int tid = threadIdx.x;
  const int w = tid >> 6, l = tid & 63;
  const int g = l >> 4, c = l & 15;
  const int bh = blockIdx.x * 16 + w * 4 + g;
  const int b = bh >> 3, h = bh & 7;
  const bool rot = (c < 8);   // d = 4c..4c+3 < 32

  const float LN1E4_32 = 9.210340371976184f * (1.f/32.f);
  float inv0 = __expf(-(float)(4*c)     * LN1E4_32);
  float inv1 = __expf(-(float)(4*c + 2) * LN1E4_32);
  float cs0[4], sn0[4], cs1[4], sn1[4];
  #pragma unroll
  for (int t = 0; t < 4; t++) {
    __sincosf((float)t * inv0, &sn0[t], &cs0[t]);
    __sincosf((float)t * inv1, &sn1[t], &cs1[t]);
  }
  float rb[4];
  #pragma unroll
  for (int t = 0; t < 4; t++) rb[t] = ldf(rel_emb, (size_t)t * 8 + h, b16);

  float q[4][4];
  #pragma unroll
  for (int i = 0; i < 4; i++) {
    bf16x4 qv = *(const bf16x4*)(qkv + ((size_t)(b*NTOK + i)) * 640 + h*DH + c*4);
    float v0 = (float)qv[0], v1 = (float)qv[1], v2 = (float)qv[2], v3 = (float)qv[3];
    if (rot) {
      float n0 = v0*cs0[i] - v1*sn0[i], n1 = v1*cs0[i] + v0*sn0[i];
      float n2 = v2*cs1[i] - v3*sn1[i], n3 = v3*cs1[i] + v2*sn1[i];
      v0 = n0; v1 = n1; v2 = n2; v3 = n3;
    }
    q[i][0] = v0; q[i][1] = v1; q[i][2] = v2; q[i][3] = v3;
  }
  #pragma unroll
  for (int i = 0; i < 4; i++) {
    float ss = q[i][0]*q[i][0] + q[i][1]*q[i][1] + q[i][2]*q[i][2] + q[i][3]*q[i][3];
    float r = 1.f / fmaxf(sqrtf(gsum16(ss)), 1e-12f);
    #pragma unroll
    for (int e = 0; e < 4; e++) q[i][e] *= r;
  }

  float kk[5][4], vv[5][4];
  #pragma unroll
  for (int e = 0; e < 4; e++) {
    kk[0][e] = ldf(nkv_all, (size_t)layer*128 + c*4 + e, b16);
    vv[0][e] = ldf(nkv_all, (size_t)layer*128 + 64 + c*4 + e, b16);
  }
  #pragma unroll
  for (int j = 1; j < 5; j++) {
    const __bf16* base = qkv + ((size_t)(b*NTOK + j - 1)) * 640 + 512;
    bf16x4 kv4 = *(const bf16x4*)(base + c*4);
    bf16x4 vv4 = *(const bf16x4*)(base + 64 + c*4);
    float v0 = (float)kv4[0], v1 = (float)kv4[1], v2 = (float)kv4[2], v3 = (float)kv4[3];
    if (rot) {
      int t = j - 1;
      float n0 = v0*cs0[t] - v1*sn0[t], n1 = v1*cs0[t] + v0*sn0[t];
      float n2 = v2*cs1[t] - v3*sn1[t], n3 = v3*cs1[t] + v2*sn1[t];
      v0 = n0; v1 = n1; v2 = n2; v3 = n3;
    }
    kk[j][0] = v0; kk[j][1] = v1; kk[j][2] = v2; kk[j][3] = v3;
    #pragma unroll
    for (int e = 0; e < 4; e++) vv[j][e] = (float)vv4[e];
  }
  #pragma unroll
  for (int j = 0; j < 5; j++) {
    float ss = kk[j][0]*kk[j][0] + kk[j][1]*kk[j][1] + kk[j][2]*kk[j][2] + kk[j][3]*kk[j][3];
    float r = 1.f / fmaxf(sqrtf(gsum16(ss)), 1e-12f);
    #pragma unroll
    for (int e = 0; e < 4; e++) kk[j][e] *= r;
  }

  #pragma unroll
  for (int i = 0; i < 4; i++) {
    float sim[5];
    #pragma unroll
    for (int j = 0; j < 5; j++) {
      if (j > i + 1) break;
      float pp = q[i][0]*kk[j][0] + q[i][1]*kk[j][1] + q[i][2]*kk[j][2] + q[i][3]*kk[j][3];
      sim[j] = 16.f * gsum16(pp) + rb[(i - j > 0) ? (i - j) : 0];
    }
    float m = sim[0];
    #pragma unroll
    for (int j = 1; j < 5; j++) { if (j > i + 1) break; m = fmaxf(m, sim[j]); }
    float Z = 0.f, o0 = 0.f, o1 = 0.f, o2 = 0.f, o3 = 0.f;
    #pragma unroll
    for (int j = 0; j < 5; j++) {
      if (j > i + 1) break;
      float e = __expf(sim[j] - m);
      Z += e;
      o0 += e * vv[j][0]; o1 += e * vv[j][1]; o2 += e * vv[j][2]; o3 += e * vv[j][3];
    }
    float rz = 1.f / Z;
    bf16x4 ov = { (__bf16)(o0*rz), (__bf16)(o1*rz), (__bf16)(o2*rz), (__bf16)(o3*rz) };
    *(bf16x4*)(ao + ((size_t)(b*NTOK + i)) * DIM + h*DH + c*4) = ov;
  }
}

// ---------------- layer-11 attention: i=3 only, compact q3/ao3 ----------------
__global__ __launch_bounds__(256) void attn_kernel3(
    const __bf16* __restrict__ q3, const __bf16* __restrict__ qkv,
    const void* __restrict__ nkv_all, int layer, const void* __restrict__ rel_emb,
    __bf16* __restrict__ ao3, const int* __restrict__ flag)
{
  bool b16 = flag[0] != 0;
  const int tid = threadIdx.x;
  const int w = tid >> 6, l = tid & 63;
  const int g = l >> 4, c = l & 15;
  const int bh = blockIdx.x * 16 + w * 4 + g;
  const int b = bh >> 3, h = bh & 7;
  const bool rot = (c < 8);

  const float LN1E4_32 = 9.210340371976184f * (1.f/32.f);
  float inv0 = __expf(-(float)(4*c)     * LN1E4_32);
  float inv1 = __expf(-(float)(4*c + 2) * LN1E4_32);
  float cs0[4], sn0[4], cs1[4], sn1[4];
  #pragma unroll
  for (int t = 0; t < 4; t++) {
    __sincosf((float)t * inv0, &sn0[t], &cs0[t]);
    __sincosf((float)t * inv1, &sn1[t], &cs1[t]);
  }
  float rb[4];
  #pragma unroll
  for (int t = 0; t < 4; t++) rb[t] = ldf(rel_emb, (size_t)t * 8 + h, b16);

  // q: token-3 row only (rotary angle t=3)
  float q[4];
  {
    bf16x4 qv = *(const bf16x4*)(q3 + (size_t)b * DIM + h*DH + c*4);
    float v0 = (float)qv[0], v1 = (float)qv[1], v2 = (float)qv[2], v3 = (float)qv[3];
    if (rot) {
      float n0 = v0*cs0[3] - v1*sn0[3], n1 = v1*cs0[3] + v0*sn0[3];
      float n2 = v2*cs1[3] - v3*sn1[3], n3 = v3*cs1[3] + v2*sn1[3];
      v0 = n0; v1 = n1; v2 = n2; v3 = n3;
    }
    float ss = v0*v0 + v1*v1 + v2*v2 + v3*v3;
    float r = 1.f / fmaxf(sqrtf(gsum16(ss)), 1e-12f);
    q[0] = v0*r; q[1] = v1*r; q[2] = v2*r; q[3] = v3*r;
  }

  float kk[5][4], vv[5][4];
  #pragma unroll
  for (int e = 0; e < 4; e++) {
    kk[0][e] = ldf(nkv_all, (size_t)layer*128 + c*4 + e, b16);
    vv[0][e] = ldf(nkv_all, (size_t)layer*128 + 64 + c*4 + e, b16);
  }
  #pragma unroll
  for (int j = 1; j < 5; j++) {
    const __bf16* base = qkv + ((size_t)(b*NTOK + j - 1)) * 640 + 512;
    bf16x4 kv4 = *(const bf16x4*)(base + c*4);
    bf16x4 vv4 = *(const bf16x4*)(base + 64 + c*4);
    float v0 = (float)kv4[0], v1 = (float)kv4[1], v2 = (float)kv4[2], v3 = (float)kv4[3];
    if (rot) {
      int t = j - 1;
      float n0 = v0*cs0[t] - v1*sn0[t], n1 = v1*cs0[t] + v0*sn0[t];
      float n2 = v2*cs1[t] - v3*sn1[t], n3 = v3*cs1[t] + v2*sn1[t];
      v0 = n0; v1 = n1; v2 = n2; v3 = n3;
    }
    kk[j][0] = v0; kk[j][1] = v1; kk[j][2] = v2; kk[j][3] = v3;
    #pragma unroll
    for (int e = 0; e < 4; e++) vv[j][e] = (float)vv4[e];
  }
  #pragma unroll
  for (int j = 0; j < 5; j++) {
    float ss = kk[j][0]*kk[j][0] + kk[j][1]*kk[j][1] + kk[j][2]*kk[j][2] + kk[j][3]*kk[j][3];
    float r = 1.f / fmaxf(sqrtf(gsum16(ss)), 1e-12f);
    #pragma unroll
    for (int e = 0; e < 4; e++) kk[j][e] *= r;
  }

  // i=3: all 5 kv unmasked; bucket = max(3-j,0)
  float sim[5];
  #pragma unroll
  for (int j = 0; j < 5; j++) {
    float pp = q[0]*kk[j][0] + q[1]*kk[j][1] + q[2]*kk[j][2] + q[3]*kk[j][3];
    sim[j] = 16.f * gsum16(pp) + rb[(3 - j > 0) ? (3 - j) : 0];
  }
  float m = sim[0];
  #pragma unroll
  for (int j = 1; j < 5; j++) m = fmaxf(m, sim[j]);
  float Z = 0.f, o0 = 0.f, o1 = 0.f, o2 = 0.f, o3 = 0.f;
  #pragma unroll
  for (int j = 0; j < 5; j++) {
    float e = __expf(sim[j] - m);
    Z += e;
    o0 += e * vv[j][0]; o1 += e * vv[j][1]; o2 += e * vv[j][2]; o3 += e * vv[j][3];
  }
  float rz = 1.f / Z;
  bf16x4 ov = { (__bf16)(o0*rz), (__bf16)(o1*rz), (__bf16)(o2*rz), (__bf16)(o3*rz) };
  *(bf16x4*)(ao3 + (size_t)b * DIM + h*DH + c*4) = ov;
}

// ---------------- launch ----------------
extern "C" void kernel_launch(void* const* d_in, const int* in_sizes, int n_in,
                              void* d_out, int out_size, void* d_ws, size_t ws_size,
                              hipStream_t stream) {
  const void* image_embed     = d_in[0];
  const void* text_embed      = d_in[1];
  const int*  timesteps       = (const int*)d_in[2];
  const void* time_table      = d_in[3];
  const void* learned_query   = d_in[4];
  const void* rel_emb         = d_in[5];
  const void* attn_norm_g     = d_in[6];
  const void* Wq              = d_in[7];
  const void* Wkv             = d_in[8];
  const void* null_kv         = d_in[9];
  const void* Wo              = d_in[10];
  const void* attn_out_norm_g = d_in[11];
  const void* ff_norm_g       = d_in[12];
  const void* Wff1            = d_in[13];
  const void* Wff2            = d_in[14];
  const void* final_norm_g    = d_in[15];
  const void* Wproj           = d_in[16];

  if (ws_size < WS_NEED) return;

  char* ws = (char*)d_ws;
  __bf16* wqkv = (__bf16*)(ws + OFF_WQKV);
  __bf16* wto  = (__bf16*)(ws + OFF_WTO);
  __bf16* wtf1 = (__bf16*)(ws + OFF_WTF1);   // interleaved
  __bf16* wtf2 = (__bf16*)(ws + OFF_WTF2);
  __bf16* wtp  = (__bf16*)(ws + OFF_WTP);
  float*  x    = (float*) (ws + OFF_X);
  __bf16* h    = (__bf16*)(ws + OFF_H);
  __bf16* qkv  = (__bf16*)(ws + OFF_QKV);   // also y; FF act buffer starts here
  __bf16* ao   = (__bf16*)(ws + OFF_AO);    // attn_out
  __bf16* act  = (__bf16*)(ws + OFF_QKV);   // 16384 x 2048 bf16 (67MB)
  int*    flag = (int*)   (ws + OFF_FLAG);
  // layer-11 compact buffers
  __bf16* h3    = (__bf16*)(ws + OFF_AO);                 // also h3b
  __bf16* q3    = (__bf16*)(ws + OFF_AO + 8388608);       // also hlast
  __bf16* ao3   = (__bf16*)(ws + OFF_AO + 16777216);
  __bf16* y3    = (__bf16*)(ws + OFF_AO + 25165824);
  float*  x3    = (float*) (ws + OFF_H);                  // h dead by then
  __bf16* act3  = (__bf16*)(ws + OFF_QKV);                // kv dead by then

  detect_dtype<<<1, 256, 0, stream>>>((const unsigned int*)Wq, flag);

  dim3 tb(32, 8);
  transpose_any<<<dim3(16, 16, 12),  tb, 0, stream>>>(Wq,   (u16*)wqkv, 512,  512,  640ull*512, 0,   0, flag);
  transpose_any<<<dim3(4,  16, 12),  tb, 0, stream>>>(Wkv,  (u16*)wqkv, 512,  128,  640ull*512, 512, 0, flag);
  transpose_any<<<dim3(16, 16, 12),  tb, 0, stream>>>(Wo,   (u16*)wto,  512,  512,  512ull*512, 0,   0, flag);
  transpose_any<<<dim3(128,16, 12),  tb, 0, stream>>>(Wff1, (u16*)wtf1, 512,  4096, 4096ull*512,0,   1, flag);
  transpose_any<<<dim3(16, 64, 12),  tb, 0, stream>>>(Wff2, (u16*)wtf2, 2048, 512,  512ull*2048,0,   0, flag);
  transpose_any<<<dim3(16, 16, 1),   tb, 0, stream>>>(Wproj,(u16*)wtp,  512,  512,  512ull*512, 0,   0, flag);

  build_tokens<<<BATCH, 256, 0, stream>>>(text_embed, image_embed, timesteps, time_table,
                                          learned_query, x, flag);

  for (int l = 0; l < DEPTH - 1; l++) {
    const __bf16* wqkv_l = wqkv + (size_t)l * 640 * 512;
    const __bf16* wto_l  = wto  + (size_t)l * 512 * 512;
    const __bf16* wtf1_l = wtf1 + (size_t)l * 4096 * 512;
    const __bf16* wtf2_l = wtf2 + (size_t)l * 512 * 2048;

    ln_f32_bf16<<<ROWS, 256, 0, stream>>>(x, attn_norm_g, (size_t)l*DIM, h, flag);
    gemm8<128,0><<<dim3(5, 128), 512, 0, stream>>>(h, DIM, wqkv_l, 512, qkv, 640, 512, flag);
    attn_kernel<<<BATCH/2, 256, 0, stream>>>(qkv, null_kv, l, rel_emb, ao, flag);
    gemm8<128,0><<<dim3(4, 128), 512, 0, stream>>>(ao, DIM, wto_l, 512, qkv /*y*/, DIM, 512, flag);
    ln_add_ln<<<ROWS, 256, 0, stream>>>(qkv /*y*/, attn_out_norm_g, (size_t)l*DIM,
                                        ff_norm_g, (size_t)l*DIM, x, h, flag);

    for (int c = 0; c < 2; c++) {
      const __bf16* hc = h + (size_t)c * 16384 * DIM;
      float*        xc = x + (size_t)c * 16384 * DIM;
      gemm8<256,1><<<dim3(16, 64), 512, 0, stream>>>(hc, DIM, wtf1_l, 512, act, FFI, 512, flag);
      gemm8<128,2><<<dim3(4, 64), 512, 0, stream>>>(act, FFI, wtf2_l, FFI, xc, DIM, 2048, flag);
    }
  }

  // ---- layer 11: only token-3 rows survive to the output ----
  {
    const int l = DEPTH - 1;
    const __bf16* wq_l   = wqkv + (size_t)l * 640 * 512;       // q rows 0-511
    const __bf16* wkv_l  = wq_l + (size_t)512 * 512;           // kv rows 512-639
    const __bf16* wto_l  = wto  + (size_t)l * 512 * 512;
    const __bf16* wtf1_l = wtf1 + (size_t)l * 4096 * 512;
    const __bf16* wtf2_l = wtf2 + (size_t)l * 512 * 2048;

    ln_f32_bf16<<<ROWS, 256, 0, stream>>>(x, attn_norm_g, (size_t)l*DIM, h, flag);
    gather3<<<BATCH/4, 256, 0, stream>>>(h, h3);
    // kv for all tokens (writes qkv cols 512-640); q only for token-3 rows
    gemm8<128,0><<<dim3(1, 128), 512, 0, stream>>>(h, DIM, wkv_l, 512, qkv + 512, 640, 512, flag);
    gemm8<128,0><<<dim3(4, 32),  512, 0, stream>>>(h3, DIM, wq_l, 512, q3, DIM, 512, flag);
    attn_kernel3<<<BATCH*HEADS/16, 256, 0, stream>>>(q3, qkv, null_kv, l, rel_emb, ao3, flag);
    gemm8<128,0><<<dim3(4, 32), 512, 0, stream>>>(ao3, DIM, wto_l, 512, y3, DIM, 512, flag);
    ln_add3<<<BATCH, 256, 0, stream>>>(y3, attn_out_norm_g, (size_t)l*DIM,
                                       ff_norm_g, (size_t)l*DIM, x, x3, h3 /*h3b*/, flag);
    gemm8<256,1><<<dim3(16, 32), 512, 0, stream>>>(h3 /*h3b*/, DIM, wtf1_l, 512, act3, FFI, 512, flag);
    gemm8<128,2><<<dim3(4, 32), 512, 0, stream>>>(act3, FFI, wtf2_l, FFI, x3, DIM, 2048, flag);
    ln_final3<<<BATCH, 256, 0, stream>>>(x3, final_norm_g, q3 /*hlast*/, flag);
    gemm8<128,3><<<dim3(4, 32), 512, 0, stream>>>(q3 /*hlast*/, DIM, wtp, 512, d_out, DIM, 512, flag);
  }
}

// Round 15
// 4999.742 us; speedup vs baseline: 1.1426x; 1.0285x over previous
//
#include <hip/hip_runtime.h>

typedef __bf16 bf16x8 __attribute__((ext_vector_type(8)));
typedef __bf16 bf16x4 __attribute__((ext_vector_type(4)));
typedef __bf16 bf16x2 __attribute__((ext_vector_type(2)));
typedef float  f32x4  __attribute__((ext_vector_type(4)));
typedef unsigned short u16;

// ---------------- constants ----------------
#define BATCH   8192
#define NTOK    4
#define ROWS    (BATCH*NTOK)      // 32768
#define DIM     512
#define HEADS   8
#define DH      64
#define FFI     2048              // FF_INNER
#define DEPTH   12
#define LN_EPS  1e-5f

// ---------------- workspace layout (bytes) ----------------
static const size_t OFF_WQKV = 0;                               // (12, 640, 512) bf16
static const size_t SZ_WQKV  = 12ull*640*512*2;
static const size_t OFF_WTO  = OFF_WQKV + SZ_WQKV;
static const size_t SZ_WTO   = 12ull*512*512*2;
static const size_t OFF_WTF1 = OFF_WTO + SZ_WTO;                // interleaved layout (12,4096,512)
static const size_t SZ_WTF1  = 12ull*4096*512*2;
static const size_t OFF_WTF2 = OFF_WTF1 + SZ_WTF1;
static const size_t SZ_WTF2  = 12ull*512*2048*2;
static const size_t OFF_WTP  = OFF_WTF2 + SZ_WTF2;
static const size_t SZ_WTP   = 512ull*512*2;
static const size_t OFF_X    = OFF_WTP + SZ_WTP;                // f32 (32768,512)
static const size_t OFF_H    = OFF_X    + (size_t)ROWS*DIM*4;   // h full; layer-11: x3 f32 (16.8MB)
static const size_t OFF_QKV  = OFF_H    + (size_t)ROWS*DIM*2;   // (32768,640) bf16; also y; act
static const size_t OFF_AO   = OFF_QKV  + (size_t)ROWS*640*2;   // attn_out; layer-11: 4x 8.4MB slots
static const size_t OFF_FLAG = OFF_AO   + (size_t)ROWS*DIM*2;
static const size_t WS_NEED  = OFF_FLAG + 256;                  // ~266 MB
// Layer-11 compact buffers (8192x512): h3/h3b @AO+0, q3/hlast @AO+8.4M, ao3 @AO+16.8M,
// y3 @AO+25.2M. x3 (f32 16.8MB) aliases h region (dead after q3/kv GEMMs).
// act3 (8192x2048 bf16 = 33.5MB) aliases qkv region (kv dead after attn3).

// ---------------- helpers ----------------
__device__ __forceinline__ float ldf(const void* p, size_t i, bool b16) {
  return b16 ? (float)((const __bf16*)p)[i] : ((const float*)p)[i];
}

__device__ __forceinline__ void gld_lds16(const void* g, void* l) {
  __builtin_amdgcn_global_load_lds((const __attribute__((address_space(1))) void*)g,
                                   (__attribute__((address_space(3))) void*)l, 16, 0, 0);
}

// 16-lane-group sum (xor butterfly, offsets 8..1 stay within the group)
__device__ __forceinline__ float gsum16(float v) {
  #pragma unroll
  for (int o = 8; o > 0; o >>= 1) v += __shfl_xor(v, o, 64);
  return v;
}

// 256-thread block reduce of (a,b); barrier-balanced so it is safe to call twice
__device__ __forceinline__ void block_reduce2(float& a, float& b, float* sm) {
  #pragma unroll
  for (int o = 32; o > 0; o >>= 1) { a += __shfl_down(a, o, 64); b += __shfl_down(b, o, 64); }
  int lane = threadIdx.x & 63, w = threadIdx.x >> 6;
  __syncthreads();
  if (lane == 0) { sm[w] = a; sm[4+w] = b; }
  __syncthreads();
  a = sm[0]+sm[1]+sm[2]+sm[3];
  b = sm[4]+sm[5]+sm[6]+sm[7];
}

// ---------------- dtype detection: 1 block, writes flag (1 = bf16, 0 = fp32) ----------------
__global__ void detect_dtype(const unsigned int* __restrict__ w, int* __restrict__ flag) {
  __shared__ int cnt[4];
  int t = threadIdx.x;
  int c = 0;
  for (int i = t; i < 2048; i += 256) {
    unsigned int v = w[i];
    unsigned int lo = v & 0xFFFFu, hi = v >> 16;
    int elo = (int)((lo >> 7) & 0xFF), ehi = (int)((hi >> 7) & 0xFF);
    bool okl = (lo == 0u) || (elo >= 100 && elo <= 140);
    bool okh = (hi == 0u) || (ehi >= 100 && ehi <= 140);
    if (okl && okh) c++;
  }
  #pragma unroll
  for (int o = 32; o > 0; o >>= 1) c += __shfl_down(c, o, 64);
  if ((t & 63) == 0) cnt[t >> 6] = c;
  __syncthreads();
  if (t == 0) flag[0] = (cnt[0] + cnt[1] + cnt[2] + cnt[3] > 1024) ? 1 : 0;
}

// ---------------- weight transpose (K,N)->(N,K), optional ff1 interleave ----------------
__global__ void transpose_any(const void* __restrict__ in, u16* __restrict__ out,
                              int K, int N, size_t out_zsz, int rowoff, int mode,
                              const int* __restrict__ flag) {
  bool b16 = flag[0] != 0;
  __shared__ u16 tile[32][33];
  size_t iboff = (size_t)blockIdx.z * K * N;
  size_t oboff = (size_t)blockIdx.z * out_zsz;
  int n0 = blockIdx.x * 32, k0 = blockIdx.y * 32;
  int tx = threadIdx.x, ty = threadIdx.y;
  #pragma unroll
  for (int r = 0; r < 4; r++) {
    float v = ldf(in, iboff + (size_t)(k0 + ty*4 + r) * N + n0 + tx, b16);
    __bf16 bv = (__bf16)v;
    tile[ty*4+r][tx] = __builtin_bit_cast(u16, bv);
  }
  __syncthreads();
  int rbase;
  if (mode == 0) rbase = rowoff + n0;
  else {
    int s = (n0 >= 2048) ? 1 : 0;
    int np = n0 - s*2048;
    rbase = (np >> 7)*256 + ((np >> 5) & 3)*64 + s*32;   // n0 % 32 == 0
  }
  #pragma unroll
  for (int r = 0; r < 4; r++)
    out[oboff + (size_t)(rbase + ty*4 + r) * K + k0 + tx] = tile[tx][ty*4+r];
}

// ---------------- token assembly: x (B,4,512) f32 ----------------
__global__ void build_tokens(const void* __restrict__ text, const void* __restrict__ img,
                             const int* __restrict__ ts, const void* __restrict__ table,
                             const void* __restrict__ lq, float* __restrict__ x,
                             const int* __restrict__ flag) {
  bool b16 = flag[0] != 0;
  int b = blockIdx.x, t = threadIdx.x;
  float* xr = x + (size_t)b * NTOK * DIM;
  int tsb = ts[b];
  for (int e = t; e < DIM; e += 256) {
    xr[e]         = ldf(text,  (size_t)b * DIM + e, b16);
    xr[DIM + e]   = ldf(table, (size_t)tsb * DIM + e, b16);
    xr[2*DIM + e] = ldf(img,   (size_t)b * DIM + e, b16);
    xr[3*DIM + e] = ldf(lq,    (size_t)e, b16);
  }
}

// ---------------- LN: f32 row -> bf16 row ----------------
__global__ void ln_f32_bf16(const float* __restrict__ x, const void* __restrict__ g, size_t goff,
                            __bf16* __restrict__ out, const int* __restrict__ flag) {
  bool b16 = flag[0] != 0;
  __shared__ float sm[8];
  int row = blockIdx.x, t = threadIdx.x;
  float2 v = ((const float2*)(x + (size_t)row * DIM))[t];
  float s = v.x + v.y, s2 = v.x*v.x + v.y*v.y;
  block_reduce2(s, s2, sm);
  float mean = s * (1.f/DIM);
  float var  = s2 * (1.f/DIM) - mean*mean;
  float rs = rsqrtf(var + LN_EPS);
  float g0 = ldf(g, goff + 2*t, b16), g1 = ldf(g, goff + 2*t + 1, b16);
  bf16x2 o2 = { (__bf16)((v.x-mean)*rs*g0), (__bf16)((v.y-mean)*rs*g1) };
  ((bf16x2*)(out + (size_t)row * DIM))[t] = o2;
}

// ---------------- fused: x += LN(y; g1); h = LN(x; g2) ----------------
__global__ void ln_add_ln(const __bf16* __restrict__ y,
                          const void* __restrict__ g1, size_t g1off,
                          const void* __restrict__ g2, size_t g2off,
                          float* __restrict__ x, __bf16* __restrict__ h,
                          const int* __restrict__ flag) {
  bool b16 = flag[0] != 0;
  __shared__ float sm[8];
  int row = blockIdx.x, t = threadIdx.x;
  bf16x2 yv = ((const bf16x2*)(y + (size_t)row * DIM))[t];
  float v0 = (float)yv[0], v1 = (float)yv[1];
  float s = v0 + v1, s2 = v0*v0 + v1*v1;
  block_reduce2(s, s2, sm);
  float mean = s * (1.f/DIM);
  float var  = s2 * (1.f/DIM) - mean*mean;
  float rs = rsqrtf(var + LN_EPS);
  float ga = ldf(g1, g1off + 2*t, b16), gb = ldf(g1, g1off + 2*t + 1, b16);
  float2* xr = (float2*)(x + (size_t)row * DIM);
  float2 xv = xr[t];
  xv.x += (v0-mean)*rs*ga;
  xv.y += (v1-mean)*rs*gb;
  xr[t] = xv;
  float s_  = xv.x + xv.y, s2_ = xv.x*xv.x + xv.y*xv.y;
  block_reduce2(s_, s2_, sm);
  float mean2 = s_ * (1.f/DIM);
  float var2  = s2_ * (1.f/DIM) - mean2*mean2;
  float rs2 = rsqrtf(var2 + LN_EPS);
  float gc = ldf(g2, g2off + 2*t, b16), gd = ldf(g2, g2off + 2*t + 1, b16);
  bf16x2 o2 = { (__bf16)((xv.x-mean2)*rs2*gc), (__bf16)((xv.y-mean2)*rs2*gd) };
  ((bf16x2*)(h + (size_t)row * DIM))[t] = o2;
}

// ---------------- layer-11 compact: x3[r] = x[r*4+3] + LN(y3[r]); h3b[r] = LN(x3[r]) ------
__global__ void ln_add3(const __bf16* __restrict__ y3,
                        const void* __restrict__ g1, size_t g1off,
                        const void* __restrict__ g2, size_t g2off,
                        const float* __restrict__ xfull, float* __restrict__ x3,
                        __bf16* __restrict__ h3b, const int* __restrict__ flag) {
  bool b16 = flag[0] != 0;
  __shared__ float sm[8];
  int r = blockIdx.x, t = threadIdx.x;
  bf16x2 yv = ((const bf16x2*)(y3 + (size_t)r * DIM))[t];
  float v0 = (float)yv[0], v1 = (float)yv[1];
  float s = v0 + v1, s2 = v0*v0 + v1*v1;
  block_reduce2(s, s2, sm);
  float mean = s * (1.f/DIM);
  float var  = s2 * (1.f/DIM) - mean*mean;
  float rs = rsqrtf(var + LN_EPS);
  float ga = ldf(g1, g1off + 2*t, b16), gb = ldf(g1, g1off + 2*t + 1, b16);
  float2 xv = ((const float2*)(xfull + (size_t)(r*NTOK + 3) * DIM))[t];
  xv.x += (v0-mean)*rs*ga;
  xv.y += (v1-mean)*rs*gb;
  ((float2*)(x3 + (size_t)r * DIM))[t] = xv;
  float s_  = xv.x + xv.y, s2_ = xv.x*xv.x + xv.y*xv.y;
  block_reduce2(s_, s2_, sm);
  float mean2 = s_ * (1.f/DIM);
  float var2  = s2_ * (1.f/DIM) - mean2*mean2;
  float rs2 = rsqrtf(var2 + LN_EPS);
  float gc = ldf(g2, g2off + 2*t, b16), gd = ldf(g2, g2off + 2*t + 1, b16);
  bf16x2 o2 = { (__bf16)((xv.x-mean2)*rs2*gc), (__bf16)((xv.y-mean2)*rs2*gd) };
  ((bf16x2*)(h3b + (size_t)r * DIM))[t] = o2;
}

// ---------------- final LN on compact x3 rows -> hlast (8192,512) bf16 ----------------
__global__ void ln_final3(const float* __restrict__ x3, const void* __restrict__ g,
                          __bf16* __restrict__ out, const int* __restrict__ flag) {
  bool b16 = flag[0] != 0;
  __shared__ float sm[8];
  int b = blockIdx.x, t = threadIdx.x;
  float2 v = ((const float2*)(x3 + (size_t)b * DIM))[t];
  float s = v.x + v.y, s2 = v.x*v.x + v.y*v.y;
  block_reduce2(s, s2, sm);
  float mean = s * (1.f/DIM);
  float var  = s2 * (1.f/DIM) - mean*mean;
  float rs = rsqrtf(var + LN_EPS);
  float g0 = ldf(g, (size_t)2*t, b16), g1 = ldf(g, (size_t)2*t + 1, b16);
  bf16x2 o2 = { (__bf16)((v.x-mean)*rs*g0), (__bf16)((v.y-mean)*rs*g1) };
  ((bf16x2*)(out + (size_t)b * DIM))[t] = o2;
}

// ---------------- gather token-3 rows: h3[r] = h[r*4+3] ----------------
__global__ void gather3(const __bf16* __restrict__ h, __bf16* __restrict__ h3) {
  int lane = threadIdx.x & 63;
  int r = blockIdx.x * 4 + (threadIdx.x >> 6);
  *(bf16x8*)(h3 + (size_t)r * DIM + lane*8) =
      *(const bf16x8*)(h + (size_t)(r*NTOK + 3) * DIM + lane*8);
}

// ================= 8-phase pipelined GEMM (256-row tile, counted vmcnt) =================
// EXACT r6 schedule — proven optimum; do not perturb.
// EPI 0: bf16; EPI 1: swiglu (interleaved B, out cols=BROWS/2); EPI 2: f32 +=; EPI 3: per-flag.
template<int BROWS, int EPI>
__global__ __launch_bounds__(512, 2) void gemm8(
    const __bf16* __restrict__ A, int lda,
    const __bf16* __restrict__ B, int ldb,
    void* __restrict__ Cv, int ldc, int K, const int* __restrict__ flag)
{
  constexpr int UNITS = (BROWS == 256) ? 4 : 3;
  constexpr int WCN   = (BROWS == 256) ? 4 : 2;
  constexpr int M_FR  = (BROWS == 256) ? 8 : 4;
  constexpr int QM    = M_FR / 4;
  __shared__ char ldsmem[2][(256 + BROWS) * 128];

  const int tid = threadIdx.x;
  const int wid = tid >> 6, lane = tid & 63;
  const int wr = wid / WCN, wc = wid % WCN;
  const int lr = lane & 15, lc = lane >> 4;
  const int sr = tid >> 3;
  const int cs = ((tid & 7) ^ (sr & 7)) * 8;
  const int bx = blockIdx.x, by = blockIdx.y;

  const __bf16* Ab = A + (size_t)by * 256 * lda;
  const __bf16* Bb = B + (size_t)bx * BROWS * ldb;

  f32x4 acc[M_FR][4] = {};
  const int NT = K >> 6;

  char* lds0 = ldsmem[0];
  char* lds1 = ldsmem[1];

  auto stage_unit = [&](int p, int kt, int u) {
    char* base = (p ? lds1 : lds0);
    if (u < 2) {
      const __bf16* s = Ab + (size_t)(u*128 + sr) * lda + kt*64 + cs;
      char* d = base + u*16384 + (wid << 10);
      gld_lds16(s, d);
      gld_lds16(s + (size_t)64 * lda, d + 8192);
    } else {
      const __bf16* s = Bb + (size_t)((u-2)*128 + sr) * ldb + kt*64 + cs;
      char* d = base + 32768 + (u-2)*16384 + (wid << 10);
      gld_lds16(s, d);
      gld_lds16(s + (size_t)64 * ldb, d + 8192);
    }
  };

  #pragma unroll
  for (int u = 0; u < UNITS; u++) stage_unit(0, 0, u);

  const int NIT = NT >> 1;
  for (int i = 0; i < NIT; i++) {
    const int t1 = 2*i + 1;
    const int t2 = (2*i + 2 < NT) ? (2*i + 2) : 0;
    #pragma unroll
    for (int hfl = 0; hfl < 2; hfl++) {
      char* cbase = hfl ? lds1 : lds0;
      const int sp = hfl ^ 1;
      const int st = hfl ? t2 : t1;
      bf16x8 bfr[4][2];
      #pragma unroll
      for (int q = 0; q < 4; q++) {
        if (q < UNITS) stage_unit(sp, st, q);
        if (q == 0) {
          asm volatile("s_waitcnt vmcnt(2)" ::: "memory");
          asm volatile("s_barrier" ::: "memory");
          #pragma unroll
          for (int f = 0; f < 4; f++)
            #pragma unroll
            for (int kk = 0; kk < 2; kk++) {
              int row = wc*64 + f*16 + lr;
              int ch = (kk*4 + lc) ^ (lr & 7);
              bfr[f][kk] = *(const bf16x8*)(cbase + 32768 + row*128 + ch*16);
            }
        }
        bf16x8 afr[QM][2];
        #pragma unroll
        for (int m2 = 0; m2 < QM; m2++)
          #pragma unroll
          for (int kk = 0; kk < 2; kk++) {
            int row = wr*(M_FR*16) + (q*QM + m2)*16 + lr;
            int ch = (kk*4 + lc) ^ (lr & 7);
            afr[m2][kk] = *(const bf16x8*)(cbase + row*128 + ch*16);
          }
        __builtin_amdgcn_s_setprio(1);
        #pragma unroll
        for (int m2 = 0; m2 < QM; m2++)
          #pragma unroll
          for (int n = 0; n < 4; n++)
            #pragma unroll
            for (int kk = 0; kk < 2; kk++)
              acc[q*QM + m2][n] = __builtin_amdgcn_mfma_f32_16x16x32_bf16(
                  afr[m2][kk], bfr[n][kk], acc[q*QM + m2][n], 0, 0, 0);
        __builtin_amdgcn_s_setprio(0);
        asm volatile("s_barrier" ::: "memory");
      }
    }
  }

  if (EPI == 1) {
    __bf16* Ob = (__bf16*)Cv;
    const int colb = bx*128 + wc*32 + lr;
    const int rowb = by*256 + wr*128 + lc*4;
    #pragma unroll
    for (int m = 0; m < M_FR; m++)
      #pragma unroll
      for (int rr = 0; rr < 4; rr++) {
        size_t ro = (size_t)(rowb + m*16 + rr) * ldc;
        #pragma unroll
        for (int fa = 0; fa < 2; fa++) {
          float a = acc[m][fa][rr], g = acc[m][fa+2][rr];
          Ob[ro + colb + fa*16] = (__bf16)(a * g / (1.f + __expf(-g)));
        }
      }
  } else if (EPI == 2) {
    float* Xf = (float*)Cv;
    const int colb = bx*BROWS + wc*64 + lr;
    const int rowb = by*256 + wr*(M_FR*16) + lc*4;
    #pragma unroll
    for (int m = 0; m < M_FR; m++)
      #pragma unroll
      for (int rr = 0; rr < 4; rr++) {
        size_t ro = (size_t)(rowb + m*16 + rr) * ldc;
        #pragma unroll
        for (int n = 0; n < 4; n++) Xf[ro + colb + n*16] += acc[m][n][rr];
      }
  } else if (EPI == 0) {
    __bf16* Cb = (__bf16*)Cv;
    const int colb = bx*BROWS + wc*64 + lr;
    const int rowb = by*256 + wr*(M_FR*16) + lc*4;
    #pragma unroll
    for (int m = 0; m < M_FR; m++)
      #pragma unroll
      for (int rr = 0; rr < 4; rr++) {
        size_t ro = (size_t)(rowb + m*16 + rr) * ldc;
        #pragma unroll
        for (int n = 0; n < 4; n++) Cb[ro + colb + n*16] = (__bf16)acc[m][n][rr];
      }
  } else {
    bool b16o = flag[0] != 0;
    __bf16* Cb = (__bf16*)Cv;
    float*  Cf = (float*)Cv;
    const int colb = bx*BROWS + wc*64 + lr;
    const int rowb = by*256 + wr*(M_FR*16) + lc*4;
    #pragma unroll
    for (int m = 0; m < M_FR; m++)
      #pragma unroll
      for (int rr = 0; rr < 4; rr++) {
        size_t ro = (size_t)(rowb + m*16 + rr) * ldc;
        #pragma unroll
        for (int n = 0; n < 4; n++) {
          float val = acc[m][n][rr];
          if (b16o) Cb[ro + colb + n*16] = (__bf16)val; else Cf[ro + colb + n*16] = val;
        }
      }
  }
}

// ---------------- fused attention, 16-lane-group layout (layers 0..10) ----------------
__global__ __launch_bounds__(256) void attn_kernel(
    const __bf16* __restrict__ qkv,
    const void* __restrict__ nkv_all, int layer, const void* __restrict__ rel_emb,
    __bf16* __restrict__ ao, const int* __restrict__ flag)
{
  bool b16 = flag[0] != 0;
  const int tid = threadIdx.x;
  const int w = tid >> 6, l = tid & 63;
  const int g = l >> 4, c = l & 15;
  const int bh = blockIdx.x * 16 + w * 4 + g;
  const int b = bh >> 3, h = bh & 7;
  const bool rot = (c < 8);   // d = 4c..4c+3 < 32

  const float LN1E4_32 = 9.210340371976184f * (1.f/32.f);
  float inv0 = __expf(-(float)(4*c)     * LN1E4_32);
  float inv1 = __expf(-(float)(4*c + 2) * LN1E4_32);
  float cs0[4], sn0[4], cs1[4], sn1[4];
  #pragma unroll
  for (int t = 0; t < 4; t++) {
    __sincosf((float)t * inv0, &sn0[t], &cs0[t]);
    __sincosf((float)t * inv1, &sn1[t], &cs1[t]);
  }
  float rb[4];
  #pragma unroll
  for (int t = 0; t < 4; t++) rb[t] = ldf(rel_emb, (size_t)t * 8 + h, b16);

  float q[4][4];
  #pragma unroll
  for (int i = 0; i < 4; i++) {
    bf16x4 qv = *(const bf16x4*)(qkv + ((size_t)(b*NTOK + i)) * 640 + h*DH + c*4);
    float v0 = (float)qv[0], v1 = (float)qv[1], v2 = (float)qv[2], v3 = (float)qv[3];
    if (rot) {
      float n0 = v0*cs0[i] - v1*sn0[i], n1 = v1*cs0[i] + v0*sn0[i];
      float n2 = v2*cs1[i] - v3*sn1[i], n3 = v3*cs1[i] + v2*sn1[i];
      v0 = n0; v1 = n1; v2 = n2; v3 = n3;
    }
    q[i][0] = v0; q[i][1] = v1; q[i][2] = v2; q[i][3] = v3;
  }
  #pragma unroll
  for (int i = 0; i < 4; i++) {
    float ss = q[i][0]*q[i][0] + q[i][1]*q[i][1] + q[i][2]*q[i][2] + q[i][3]*q[i][3];
    float r = 1.f / fmaxf(sqrtf(gsum16(ss)), 1e-12f);
    #pragma unroll
    for (int e = 0; e < 4; e++) q[i][e] *= r;
  }

  float kk[5][4], vv[5][4];
  #pragma unroll
  for (int e = 0; e < 4; e++) {
    kk[0][e] = ldf(nkv_all, (size_t)layer*128 + c*4 + e, b16);
    vv[0][e] = ldf(nkv_all, (size_t)layer*128 + 64 + c*4 + e, b16);
  }
  #pragma unroll
  for (int j = 1; j < 5; j++) {
    const __bf16* base = qkv + ((size_t)(b*NTOK + j - 1)) * 640 + 512;
    bf16x4 kv4 = *(const bf16x4*)(base + c*4);
    bf16x4 vv4 = *(const bf16x4*)(base + 64 + c*4);
    float v0 = (float)kv4[0], v1 = (float)kv4[1], v2 = (float)kv4[2], v3 = (float)kv4[3];
    if (rot) {
      int t = j - 1;
      float n0 = v0*cs0[t] - v1*sn0[t], n1 = v1*cs0[t] + v0*sn0[t];
      float n2 = v2*cs1[t] - v3*sn1[t], n3 = v3*cs1[t] + v2*sn1[t];
      v0 = n0; v1 = n1; v2 = n2; v3 = n3;
    }
    kk[j][0] = v0; kk[j][1] = v1; kk[j][2] = v2; kk[j][3] = v3;
    #pragma unroll
    for (int e = 0; e < 4; e++) vv[j][e] = (float)vv4[e];
  }
  #pragma unroll
  for (int j = 0; j < 5; j++) {
    float ss = kk[j][0]*kk[j][0] + kk[j][1]*kk[j][1] + kk[j][2]*kk[j][2] + kk[j][3]*kk[j][3];
    float r = 1.f / fmaxf(sqrtf(gsum16(ss)), 1e-12f);
    #pragma unroll
    for (int e = 0; e < 4; e++) kk[j][e] *= r;
  }

  #pragma unroll
  for (int i = 0; i < 4; i++) {
    float sim[5];
    #pragma unroll
    for (int j = 0; j < 5; j++) {
      if (j > i + 1) break;
      float pp = q[i][0]*kk[j][0] + q[i][1]*kk[j][1] + q[i][2]*kk[j][2] + q[i][3]*kk[j][3];
      sim[j] = 16.f * gsum16(pp) + rb[(i - j > 0) ? (i - j) : 0];
    }
    float m = sim[0];
    #pragma unroll
    for (int j = 1; j < 5; j++) { if (j > i + 1) break; m = fmaxf(m, sim[j]); }
    float Z = 0.f, o0 = 0.f, o1 = 0.f, o2 = 0.f, o3 = 0.f;
    #pragma unroll
    for (int j = 0; j < 5; j++) {
      if (j > i + 1) break;
      float e = __expf(sim[j] - m);
      Z += e;
      o0 += e * vv[j][0]; o1 += e * vv[j][1]; o2 += e * vv[j][2]; o3 += e * vv[j][3];
    }
    float rz = 1.f / Z;
    bf16x4 ov = { (__bf16)(o0*rz), (__bf16)(o1*rz), (__bf16)(o2*rz), (__bf16)(o3*rz) };
    *(bf16x4*)(ao + ((size_t)(b*NTOK + i)) * DIM + h*DH + c*4) = ov;
  }
}

// ---------------- layer-11 attention: i=3 only, compact q3/ao3 ----------------
__global__ __launch_bounds__(256) void attn_kernel3(
    const __bf16* __restrict__ q3, const __bf16* __restrict__ qkv,
    const void* __restrict__ nkv_all, int layer, const void* __restrict__ rel_emb,
    __bf16* __restrict__ ao3, const int* __restrict__ flag)
{
  bool b16 = flag[0] != 0;
  const int tid = threadIdx.x;
  const int w = tid >> 6, l = tid & 63;
  const int g = l >> 4, c = l & 15;
  const int bh = blockIdx.x * 16 + w * 4 + g;
  const int b = bh >> 3, h = bh & 7;
  const bool rot = (c < 8);

  const float LN1E4_32 = 9.210340371976184f * (1.f/32.f);
  float inv0 = __expf(-(float)(4*c)     * LN1E4_32);
  float inv1 = __expf(-(float)(4*c + 2) * LN1E4_32);
  float cs0[4], sn0[4], cs1[4], sn1[4];
  #pragma unroll
  for (int t = 0; t < 4; t++) {
    __sincosf((float)t * inv0, &sn0[t], &cs0[t]);
    __sincosf((float)t * inv1, &sn1[t], &cs1[t]);
  }
  float rb[4];
  #pragma unroll
  for (int t = 0; t < 4; t++) rb[t] = ldf(rel_emb, (size_t)t * 8 + h, b16);

  float q[4];
  {
    bf16x4 qv = *(const bf16x4*)(q3 + (size_t)b * DIM + h*DH + c*4);
    float v0 = (float)qv[0], v1 = (float)qv[1], v2 = (float)qv[2], v3 = (float)qv[3];
    if (rot) {
      float n0 = v0*cs0[3] - v1*sn0[3], n1 = v1*cs0[3] + v0*sn0[3];
      float n2 = v2*cs1[3] - v3*sn1[3], n3 = v3*cs1[3] + v2*sn1[3];
      v0 = n0; v1 = n1; v2 = n2; v3 = n3;
    }
    float ss = v0*v0 + v1*v1 + v2*v2 + v3*v3;
    float r = 1.f / fmaxf(sqrtf(gsum16(ss)), 1e-12f);
    q[0] = v0*r; q[1] = v1*r; q[2] = v2*r; q[3] = v3*r;
  }

  float kk[5][4], vv[5][4];
  #pragma unroll
  for (int e = 0; e < 4; e++) {
    kk[0][e] = ldf(nkv_all, (size_t)layer*128 + c*4 + e, b16);
    vv[0][e] = ldf(nkv_all, (size_t)layer*128 + 64 + c*4 + e, b16);
  }
  #pragma unroll
  for (int j = 1; j < 5; j++) {
    const __bf16* base = qkv + ((size_t)(b*NTOK + j - 1)) * 640 + 512;
    bf16x4 kv4 = *(const bf16x4*)(base + c*4);
    bf16x4 vv4 = *(const bf16x4*)(base + 64 + c*4);
    float v0 = (float)kv4[0], v1 = (float)kv4[1], v2 = (float)kv4[2], v3 = (float)kv4[3];
    if (rot) {
      int t = j - 1;
      float n0 = v0*cs0[t] - v1*sn0[t], n1 = v1*cs0[t] + v0*sn0[t];
      float n2 = v2*cs1[t] - v3*sn1[t], n3 = v3*cs1[t] + v2*sn1[t];
      v0 = n0; v1 = n1; v2 = n2; v3 = n3;
    }
    kk[j][0] = v0; kk[j][1] = v1; kk[j][2] = v2; kk[j][3] = v3;
    #pragma unroll
    for (int e = 0; e < 4; e++) vv[j][e] = (float)vv4[e];
  }
  #pragma unroll
  for (int j = 0; j < 5; j++) {
    float ss = kk[j][0]*kk[j][0] + kk[j][1]*kk[j][1] + kk[j][2]*kk[j][2] + kk[j][3]*kk[j][3];
    float r = 1.f / fmaxf(sqrtf(gsum16(ss)), 1e-12f);
    #pragma unroll
    for (int e = 0; e < 4; e++) kk[j][e] *= r;
  }

  float sim[5];
  #pragma unroll
  for (int j = 0; j < 5; j++) {
    float pp = q[0]*kk[j][0] + q[1]*kk[j][1] + q[2]*kk[j][2] + q[3]*kk[j][3];
    sim[j] = 16.f * gsum16(pp) + rb[(3 - j > 0) ? (3 - j) : 0];
  }
  float m = sim[0];
  #pragma unroll
  for (int j = 1; j < 5; j++) m = fmaxf(m, sim[j]);
  float Z = 0.f, o0 = 0.f, o1 = 0.f, o2 = 0.f, o3 = 0.f;
  #pragma unroll
  for (int j = 0; j < 5; j++) {
    float e = __expf(sim[j] - m);
    Z += e;
    o0 += e * vv[j][0]; o1 += e * vv[j][1]; o2 += e * vv[j][2]; o3 += e * vv[j][3];
  }
  float rz = 1.f / Z;
  bf16x4 ov = { (__bf16)(o0*rz), (__bf16)(o1*rz), (__bf16)(o2*rz), (__bf16)(o3*rz) };
  *(bf16x4*)(ao3 + (size_t)b * DIM + h*DH + c*4) = ov;
}

// ---------------- launch ----------------
extern "C" void kernel_launch(void* const* d_in, const int* in_sizes, int n_in,
                              void* d_out, int out_size, void* d_ws, size_t ws_size,
                              hipStream_t stream) {
  const void* image_embed     = d_in[0];
  const void* text_embed      = d_in[1];
  const int*  timesteps       = (const int*)d_in[2];
  const void* time_table      = d_in[3];
  const void* learned_query   = d_in[4];
  const void* rel_emb         = d_in[5];
  const void* attn_norm_g     = d_in[6];
  const void* Wq              = d_in[7];
  const void* Wkv             = d_in[8];
  const void* null_kv         = d_in[9];
  const void* Wo              = d_in[10];
  const void* attn_out_norm_g = d_in[11];
  const void* ff_norm_g       = d_in[12];
  const void* Wff1            = d_in[13];
  const void* Wff2            = d_in[14];
  const void* final_norm_g    = d_in[15];
  const void* Wproj           = d_in[16];

  if (ws_size < WS_NEED) return;

  char* ws = (char*)d_ws;
  __bf16* wqkv = (__bf16*)(ws + OFF_WQKV);
  __bf16* wto  = (__bf16*)(ws + OFF_WTO);
  __bf16* wtf1 = (__bf16*)(ws + OFF_WTF1);   // interleaved
  __bf16* wtf2 = (__bf16*)(ws + OFF_WTF2);
  __bf16* wtp  = (__bf16*)(ws + OFF_WTP);
  float*  x    = (float*) (ws + OFF_X);
  __bf16* h    = (__bf16*)(ws + OFF_H);
  __bf16* qkv  = (__bf16*)(ws + OFF_QKV);   // also y; FF act buffer starts here
  __bf16* ao   = (__bf16*)(ws + OFF_AO);    // attn_out
  __bf16* act  = (__bf16*)(ws + OFF_QKV);   // 16384 x 2048 bf16 (67MB)
  int*    flag = (int*)   (ws + OFF_FLAG);
  // layer-11 compact buffers
  __bf16* h3    = (__bf16*)(ws + OFF_AO);                 // also h3b
  __bf16* q3    = (__bf16*)(ws + OFF_AO + 8388608);       // also hlast
  __bf16* ao3   = (__bf16*)(ws + OFF_AO + 16777216);
  __bf16* y3    = (__bf16*)(ws + OFF_AO + 25165824);
  float*  x3    = (float*) (ws + OFF_H);                  // h dead by then
  __bf16* act3  = (__bf16*)(ws + OFF_QKV);                // kv dead by then

  detect_dtype<<<1, 256, 0, stream>>>((const unsigned int*)Wq, flag);

  dim3 tb(32, 8);
  transpose_any<<<dim3(16, 16, 12),  tb, 0, stream>>>(Wq,   (u16*)wqkv, 512,  512,  640ull*512, 0,   0, flag);
  transpose_any<<<dim3(4,  16, 12),  tb, 0, stream>>>(Wkv,  (u16*)wqkv, 512,  128,  640ull*512, 512, 0, flag);
  transpose_any<<<dim3(16, 16, 12),  tb, 0, stream>>>(Wo,   (u16*)wto,  512,  512,  512ull*512, 0,   0, flag);
  transpose_any<<<dim3(128,16, 12),  tb, 0, stream>>>(Wff1, (u16*)wtf1, 512,  4096, 4096ull*512,0,   1, flag);
  transpose_any<<<dim3(16, 64, 12),  tb, 0, stream>>>(Wff2, (u16*)wtf2, 2048, 512,  512ull*2048,0,   0, flag);
  transpose_any<<<dim3(16, 16, 1),   tb, 0, stream>>>(Wproj,(u16*)wtp,  512,  512,  512ull*512, 0,   0, flag);

  build_tokens<<<BATCH, 256, 0, stream>>>(text_embed, image_embed, timesteps, time_table,
                                          learned_query, x, flag);

  for (int l = 0; l < DEPTH - 1; l++) {
    const __bf16* wq_l   = wqkv + (size_t)l * 640 * 512;       // q rows 0-511
    const __bf16* wkv_l  = wq_l + (size_t)512 * 512;           // kv rows 512-639
    const __bf16* wto_l  = wto  + (size_t)l * 512 * 512;
    const __bf16* wtf1_l = wtf1 + (size_t)l * 4096 * 512;
    const __bf16* wtf2_l = wtf2 + (size_t)l * 512 * 2048;

    ln_f32_bf16<<<ROWS, 256, 0, stream>>>(x, attn_norm_g, (size_t)l*DIM, h, flag);
    // q: BROWS=256 (A restaged 2x instead of 5x); kv: BROWS=128
    gemm8<256,0><<<dim3(2, 128), 512, 0, stream>>>(h, DIM, wq_l, 512, qkv, 640, 512, flag);
    gemm8<128,0><<<dim3(1, 128), 512, 0, stream>>>(h, DIM, wkv_l, 512, qkv + 512, 640, 512, flag);
    attn_kernel<<<BATCH/2, 256, 0, stream>>>(qkv, null_kv, l, rel_emb, ao, flag);
    // Wo: BROWS=256 (A restaged 2x instead of 4x)
    gemm8<256,0><<<dim3(2, 128), 512, 0, stream>>>(ao, DIM, wto_l, 512, qkv /*y*/, DIM, 512, flag);
    ln_add_ln<<<ROWS, 256, 0, stream>>>(qkv /*y*/, attn_out_norm_g, (size_t)l*DIM,
                                        ff_norm_g, (size_t)l*DIM, x, h, flag);

    for (int c = 0; c < 2; c++) {
      const __bf16* hc = h + (size_t)c * 16384 * DIM;
      float*        xc = x + (size_t)c * 16384 * DIM;
      gemm8<256,1><<<dim3(16, 64), 512, 0, stream>>>(hc, DIM, wtf1_l, 512, act, FFI, 512, flag);
      gemm8<128,2><<<dim3(4, 64), 512, 0, stream>>>(act, FFI, wtf2_l, FFI, xc, DIM, 2048, flag);
    }
  }

  // ---- layer 11: only token-3 rows survive to the output ----
  {
    const int l = DEPTH - 1;
    const __bf16* wq_l   = wqkv + (size_t)l * 640 * 512;
    const __bf16* wkv_l  = wq_l + (size_t)512 * 512;
    const __bf16* wto_l  = wto  + (size_t)l * 512 * 512;
    const __bf16* wtf1_l = wtf1 + (size_t)l * 4096 * 512;
    const __bf16* wtf2_l = wtf2 + (size_t)l * 512 * 2048;

    ln_f32_bf16<<<ROWS, 256, 0, stream>>>(x, attn_norm_g, (size_t)l*DIM, h, flag);
    gather3<<<BATCH/4, 256, 0, stream>>>(h, h3);
    gemm8<128,0><<<dim3(1, 128), 512, 0, stream>>>(h, DIM, wkv_l, 512, qkv + 512, 640, 512, flag);
    gemm8<128,0><<<dim3(4, 32),  512, 0, stream>>>(h3, DIM, wq_l, 512, q3, DIM, 512, flag);
    attn_kernel3<<<BATCH*HEADS/16, 256, 0, stream>>>(q3, qkv, null_kv, l, rel_emb, ao3, flag);
    gemm8<128,0><<<dim3(4, 32), 512, 0, stream>>>(ao3, DIM, wto_l, 512, y3, DIM, 512, flag);
    ln_add3<<<BATCH, 256, 0, stream>>>(y3, attn_out_norm_g, (size_t)l*DIM,
                                       ff_norm_g, (size_t)l*DIM, x, x3, h3 /*h3b*/, flag);
    gemm8<256,1><<<dim3(16, 32), 512, 0, stream>>>(h3 /*h3b*/, DIM, wtf1_l, 512, act3, FFI, 512, flag);
    gemm8<128,2><<<dim3(4, 32), 512, 0, stream>>>(act3, FFI, wtf2_l, FFI, x3, DIM, 2048, flag);
    ln_final3<<<BATCH, 256, 0, stream>>>(x3, final_norm_g, q3 /*hlast*/, flag);
    gemm8<128,3><<<dim3(4, 32), 512, 0, stream>>>(q3 /*hlast*/, DIM, wtp, 512, d_out, DIM, 512, flag);
  }
}